// Round 2
// baseline (8674.140 us; speedup 1.0000x reference)
//
#include <hip/hip_runtime.h>
#include <hip/hip_bf16.h>
#include <math.h>

// ---------------- problem constants ----------------
#define BATCH 8
#define NCELLS 196          // 14*14
#define NCLS 20
#define HEADC 25            // 1 + 20 + 4

// ---------------- weight transpose: [co][ci][k] -> [ci][k][co] ----------------
template<int CIN, int COUT>
__global__ void transpose_w(const float* __restrict__ w, float* __restrict__ wt) {
    const int n = CIN * COUT * 9;
    for (int i = blockIdx.x * blockDim.x + threadIdx.x; i < n; i += gridDim.x * blockDim.x) {
        int k  = i % 9;
        int ci = (i / 9) % CIN;
        int co = i / (9 * CIN);
        wt[((size_t)ci * 9 + k) * COUT + co] = w[i];
    }
}

// ---------------- conv1: 3->64, 448->224, stride 2, SAME(pad_lo=0,pad_hi=1), ReLU ----------------
__global__ void conv1_kernel(const float* __restrict__ x, const float* __restrict__ w1,
                             float* __restrict__ out) {
    __shared__ float sW[27][64];
    for (int e = threadIdx.x; e < 1728; e += 256) {
        int k = e >> 6, co = e & 63;
        sW[k][co] = w1[co * 27 + k];
    }
    __syncthreads();
    int t = blockIdx.x * 256 + threadIdx.x;     // covers 8*8*224*224 exactly
    int ox  = t % 224;
    int rem = t / 224;
    int oy  = rem % 224;
    rem /= 224;
    int cog = rem & 7;
    int b   = rem >> 3;
    float acc[8] = {0.f,0.f,0.f,0.f,0.f,0.f,0.f,0.f};
    for (int ci = 0; ci < 3; ci++) {
        #pragma unroll
        for (int ky = 0; ky < 3; ky++) {
            int iy = 2 * oy + ky;
            if (iy >= 448) continue;
            #pragma unroll
            for (int kx = 0; kx < 3; kx++) {
                int ix = 2 * ox + kx;
                if (ix >= 448) continue;
                float iv = x[(((size_t)b * 3 + ci) * 448 + iy) * 448 + ix];
                int k = (ci * 3 + ky) * 3 + kx;
                float4 wa = *(const float4*)&sW[k][cog * 8];
                float4 wb = *(const float4*)&sW[k][cog * 8 + 4];
                acc[0] += wa.x * iv; acc[1] += wa.y * iv; acc[2] += wa.z * iv; acc[3] += wa.w * iv;
                acc[4] += wb.x * iv; acc[5] += wb.y * iv; acc[6] += wb.z * iv; acc[7] += wb.w * iv;
            }
        }
    }
    #pragma unroll
    for (int u = 0; u < 8; u++)
        out[(((size_t)b * 64 + cog * 8 + u) * 224 + oy) * 224 + ox] = fmaxf(acc[u], 0.f);
}

// ---------------- generic 3x3 stride-2 SAME conv, tiled, register-prefetch pipelined ----------------
// Tile: 64 co x (16x16) px per block of 256 threads; thread = 8co x 8px.
// Chunk loop: global loads for chunk k+1 issued into registers BEFORE compute of chunk k,
// so the vmcnt drain at the next ds_write phase lands after ~9K cycles of FMA.
template<int CIN, int COUT, int HIN, int WIN, int KSPLIT, bool PARTIAL>
__launch_bounds__(256, 3)
__global__ void conv3x3s2(const float* __restrict__ in, const float* __restrict__ wt,
                          float* __restrict__ out) {
    constexpr int HOUT = HIN / 2, WOUT = WIN / 2;
    constexpr int NT   = (HOUT + 15) / 16;
    constexpr int COCH = COUT / 64;
    constexpr int KC   = 4;
    constexpr int CPS  = CIN / KSPLIT;          // channels per split
    constexpr int NCH  = CPS / KC;              // chunks per block
    constexpr size_t PSZ = (size_t)BATCH * COUT * HOUT * WOUT;
    constexpr int NIN  = KC * 33 * 33;          // 4356
    constexpr int NLD  = (NIN + 255) / 256;     // 18
    constexpr int NW   = KC * 9 * 64 / 256;     // 9 (exact)

    __shared__ float sIn[KC][33][64];
    __shared__ float sW_[KC * 9 * 64];

    int bid = blockIdx.x;
    int ks  = bid % KSPLIT; bid /= KSPLIT;
    int tx  = bid % NT;     bid /= NT;
    int ty  = bid % NT;     bid /= NT;
    int cch = bid % COCH;
    int b   = bid / COCH;
    int cb  = cch * 64;

    const int tid  = threadIdx.x;
    const int cog  = tid >> 5;          // 0..7
    const int pxg  = tid & 31;          // 0..31
    const int row  = pxg >> 1;          // 0..15
    const int half = pxg & 1;           // 0..1

    // ---- precompute per-thread load descriptors (once) ----
    int goff[NLD];      // global offset within a KC-channel slab, -1 if no load
    int laddr[NLD];     // flat LDS float index (swizzled), -1 if no slot
    #pragma unroll
    for (int m = 0; m < NLD; m++) {
        int e   = tid + m * 256;
        int c   = e / 1089;
        int rem = e - c * 1089;
        int liy = rem / 33;
        int lix = rem - liy * 33;
        int iy  = ty * 32 + liy;
        int ix  = tx * 32 + lix;
        bool inrange = (e < NIN);
        bool ok = inrange && (iy < HIN) && (ix < WIN);
        goff[m]  = ok ? (c * HIN * WIN + iy * WIN + ix) : -1;
        int pl   = (lix & 3) | ((((lix >> 2) ^ (liy & 15)) << 2));
        laddr[m] = inrange ? (c * 33 * 64 + liy * 64 + pl) : -1;
    }
    int woff[NW];
    #pragma unroll
    for (int m = 0; m < NW; m++) {
        int e   = tid + m * 256;
        int c   = e / 576;
        int rem = e - c * 576;
        int k   = rem >> 6;
        int co  = rem & 63;
        woff[m] = c * 9 * COUT + k * COUT + cb + co;
    }

    const float* inb = in + (size_t)(b * CIN + ks * CPS) * HIN * WIN;
    const float* wtb = wt + (size_t)(ks * CPS) * 9 * COUT;

    // ---- prefetch chunk 0 into registers ----
    float rIn[NLD], rW[NW];
    #pragma unroll
    for (int m = 0; m < NLD; m++) rIn[m] = (goff[m] >= 0) ? inb[goff[m]] : 0.f;
    #pragma unroll
    for (int m = 0; m < NW; m++)  rW[m]  = wtb[woff[m]];

    float acc[8][8];
    #pragma unroll
    for (int u = 0; u < 8; u++)
        #pragma unroll
        for (int j = 0; j < 8; j++) acc[u][j] = 0.f;

    for (int ch = 0; ch < NCH; ch++) {
        __syncthreads();                 // previous compute done reading LDS
        // ---- regs -> LDS ----
        #pragma unroll
        for (int m = 0; m < NLD; m++)
            if (laddr[m] >= 0) ((float*)sIn)[laddr[m]] = rIn[m];
        #pragma unroll
        for (int m = 0; m < NW; m++) sW_[tid + m * 256] = rW[m];
        __syncthreads();
        // ---- issue global prefetch for next chunk (results needed only at next ds_write) ----
        if (ch + 1 < NCH) {
            const float* inc = inb + (size_t)(ch + 1) * KC * HIN * WIN;
            const float* wtc = wtb + (size_t)(ch + 1) * KC * 9 * COUT;
            #pragma unroll
            for (int m = 0; m < NLD; m++) rIn[m] = (goff[m] >= 0) ? inc[goff[m]] : 0.f;
            #pragma unroll
            for (int m = 0; m < NW; m++)  rW[m]  = wtc[woff[m]];
        }
        // ---- compute ----
        #pragma unroll
        for (int c = 0; c < KC; c++) {
            #pragma unroll
            for (int ky = 0; ky < 3; ky++) {
                int liy = 2 * row + ky;
                int s   = liy & 15;
                float rin[20];
                #pragma unroll
                for (int m = 0; m < 5; m++) {
                    int pb = ((4 * half + m) ^ s) << 2;
                    float4 v = *(const float4*)&sIn[c][liy][pb];
                    rin[4 * m + 0] = v.x; rin[4 * m + 1] = v.y;
                    rin[4 * m + 2] = v.z; rin[4 * m + 3] = v.w;
                }
                #pragma unroll
                for (int kx = 0; kx < 3; kx++) {
                    const float* wp = &sW_[(c * 9 + ky * 3 + kx) * 64 + cog * 8];
                    float wreg[8];
                    *(float4*)&wreg[0] = *(const float4*)wp;
                    *(float4*)&wreg[4] = *(const float4*)(wp + 4);
                    #pragma unroll
                    for (int jj = 0; jj < 8; jj++) {
                        float iv = rin[2 * jj + kx];
                        #pragma unroll
                        for (int u = 0; u < 8; u++) acc[u][jj] += wreg[u] * iv;
                    }
                }
            }
        }
    }
    // ---- store ----
    int oy  = ty * 16 + row;
    int oxb = tx * 16 + half * 8;
    if (oy < HOUT) {
        #pragma unroll
        for (int u = 0; u < 8; u++) {
            size_t rowbase = (((size_t)b * COUT + cb + cog * 8 + u) * HOUT + oy) * WOUT;
            #pragma unroll
            for (int jj = 0; jj < 8; jj++) {
                int ox = oxb + jj;
                if (ox < WOUT) {
                    if (PARTIAL) out[(size_t)ks * PSZ + rowbase + ox] = acc[u][jj];
                    else         out[rowbase + ox] = fmaxf(acc[u][jj], 0.f);
                }
            }
        }
    }
}

// ---------------- deterministic K-split reduction (+ReLU) ----------------
template<int KS>
__global__ void reduceN_relu(const float* __restrict__ p, float* __restrict__ o, int n) {
    int i = blockIdx.x * 256 + threadIdx.x;
    if (i < n) {
        float s = 0.f;
        #pragma unroll
        for (int k = 0; k < KS; k++) s += p[(size_t)k * n + i];
        o[i] = fmaxf(s, 0.f);
    }
}

// ---------------- 1x1 head: wave per cell, lanes split ci ----------------
__global__ void head_kernel(const float* __restrict__ act, const float* __restrict__ wh,
                            float* __restrict__ pred) {
    int wave = threadIdx.x >> 6;
    int lane = threadIdx.x & 63;
    int cellid = blockIdx.x * 4 + wave;          // 0..1567
    int b = cellid / NCELLS, cell = cellid % NCELLS;
    float acc[HEADC];
    #pragma unroll
    for (int c = 0; c < HEADC; c++) acc[c] = 0.f;
    for (int it = 0; it < 8; it++) {
        int ci = it * 64 + lane;
        float a = act[((size_t)b * 512 + ci) * NCELLS + cell];
        #pragma unroll
        for (int c = 0; c < HEADC; c++) acc[c] += a * wh[c * 512 + ci];
    }
    #pragma unroll
    for (int c = 0; c < HEADC; c++) {
        float v = acc[c];
        v += __shfl_down(v, 32); v += __shfl_down(v, 16); v += __shfl_down(v, 8);
        v += __shfl_down(v, 4);  v += __shfl_down(v, 2);  v += __shfl_down(v, 1);
        if (lane == 0) pred[(size_t)cellid * HEADC + c] = v;
    }
}

// ---------------- decode: sigmoid/softmax/boxes ----------------
__global__ void decode_kernel(const float* __restrict__ pred, float* __restrict__ out,
                              float* __restrict__ cls) {
    int i = blockIdx.x * 256 + threadIdx.x;
    if (i >= BATCH * NCELLS) return;
    const float* p = pred + (size_t)i * HEADC;
    int cell = i % NCELLS;
    int gx = cell % 14, gy = cell / 14;
    float conf = 1.f / (1.f + expf(-p[0]));
    float m = p[1];
    #pragma unroll
    for (int c = 1; c < NCLS; c++) m = fmaxf(m, p[1 + c]);
    float e[NCLS], s = 0.f;
    #pragma unroll
    for (int c = 0; c < NCLS; c++) { e[c] = expf(p[1 + c] - m); s += e[c]; }
    float inv = conf / s;
    #pragma unroll
    for (int c = 0; c < NCLS; c++) cls[(size_t)i * NCLS + c] = e[c] * inv;
    float cx = (1.f / (1.f + expf(-p[21])) + gx) * 32.f;
    float cy = (1.f / (1.f + expf(-p[22])) + gy) * 32.f;
    float w  = expf(p[23]) * 32.f;
    float h  = expf(p[24]) * 32.f;
    float x1 = (cx - 0.5f * w) / 448.f, y1 = (cy - 0.5f * h) / 448.f;
    float x2 = (cx + 0.5f * w) / 448.f, y2 = (cy + 0.5f * h) / 448.f;
    x1 = fminf(fmaxf(x1, 0.f), 1.f); y1 = fminf(fmaxf(y1, 0.f), 1.f);
    x2 = fminf(fmaxf(x2, 0.f), 1.f); y2 = fminf(fmaxf(y2, 0.f), 1.f);
    float* o = out + (size_t)i * 24;
    o[0] = x1; o[1] = y1; o[2] = x2; o[3] = y2;
}

// ---------------- IoU matrices (per batch, 196x196) ----------------
__global__ void iou_kernel(const float* __restrict__ out, float* __restrict__ iou) {
    int idx = blockIdx.x * 256 + threadIdx.x;
    if (idx >= BATCH * NCELLS * NCELLS) return;
    int j = idx % NCELLS;
    int i = (idx / NCELLS) % NCELLS;
    int b = idx / (NCELLS * NCELLS);
    const float* bi = out + (((size_t)b * NCELLS) + i) * 24;
    const float* bj = out + (((size_t)b * NCELLS) + j) * 24;
    float ai = fmaxf(bi[2] - bi[0], 0.f) * fmaxf(bi[3] - bi[1], 0.f);
    float aj = fmaxf(bj[2] - bj[0], 0.f) * fmaxf(bj[3] - bj[1], 0.f);
    float ix1 = fmaxf(bi[0], bj[0]), iy1 = fmaxf(bi[1], bj[1]);
    float ix2 = fminf(bi[2], bj[2]), iy2 = fminf(bi[3], bj[3]);
    float inter = fmaxf(ix2 - ix1, 0.f) * fmaxf(iy2 - iy1, 0.f);
    iou[idx] = inter / (ai + aj - inter + 1e-14f);
}

// ---------------- per-(batch,class) greedy NMS + final score write ----------------
__global__ void nms_kernel(const float* __restrict__ cls, const float* __restrict__ iou,
                           float* __restrict__ out) {
    int b = blockIdx.x / NCLS;
    int c = blockIdx.x % NCLS;
    __shared__ float sc[NCELLS];
    __shared__ float ssort[NCELLS];
    __shared__ int   ord[NCELLS];
    __shared__ int   kp[NCELLS];
    int j = threadIdx.x;
    float sj = 0.f;
    if (j < NCELLS) {
        sj = cls[(((size_t)b * NCELLS) + j) * NCLS + c];
        sc[j] = sj;
    }
    __syncthreads();
    if (j < NCELLS) {
        int r = 0;
        for (int k = 0; k < NCELLS; k++) {
            float sk = sc[k];
            r += (sk > sj) || (sk == sj && k < j);   // stable descending rank
        }
        ord[r] = j; ssort[r] = sj; kp[r] = (sj > 0.01f) ? 1 : 0;
    }
    __syncthreads();
    int myo = (j < NCELLS) ? ord[j] : 0;
    const float* iob = iou + (size_t)b * NCELLS * NCELLS;
    for (int i = 0; i < NCELLS; i++) {
        __syncthreads();
        if (!kp[i]) continue;                        // uniform branch
        if (j > i && j < NCELLS && kp[j]) {
            if (iob[ord[i] * NCELLS + myo] > 0.5f) kp[j] = 0;
        }
    }
    __syncthreads();
    if (j < NCELLS)
        out[(((size_t)b * NCELLS) + ord[j]) * 24 + 4 + c] = kp[j] ? ssort[j] : 0.f;
}

// ---------------- launch ----------------
extern "C" void kernel_launch(void* const* d_in, const int* in_sizes, int n_in,
                              void* d_out, int out_size, void* d_ws, size_t ws_size,
                              hipStream_t stream) {
    const float* x  = (const float*)d_in[0];
    const float* w1 = (const float*)d_in[1];
    const float* w2 = (const float*)d_in[2];
    const float* w3 = (const float*)d_in[3];
    const float* w4 = (const float*)d_in[4];
    const float* w5 = (const float*)d_in[5];
    const float* wh = (const float*)d_in[6];
    float* out = (float*)d_out;
    float* ws  = (float*)d_ws;

    // workspace layout (float offsets) — total 42,442,752 floats (~170 MB), same as R0
    float* act1  = ws;                       // 25,690,112  (dead after conv2)
    float* act2  = ws + 25690112;            // 12,845,056  (dead after conv3)
    float* part3 = ws;                       // 2 x 6,422,528  (overlays dead act1)
    float* act3  = ws + 12845056;            // 6,422,528
    float* part4 = ws + 25690112;            // 4 x 3,211,264  (overlays dead act2)
    float* act4  = ws + 19267584;            // 3,211,264
    float* part5 = ws;                       // 16 x 802,816   (overlays dead part3)
    float* act5  = ws + 22478848;            // 802,816
    float* pred  = ws + 23281664;            // 39,200
    float* clsb  = ws + 23320864;            // 31,360
    float* ioub  = ws + 23352224;            // 307,328
    float* WT    = ws + 38535168;            // transposed weights, 3,907,584 total
    float* wt2 = WT;
    float* wt3 = WT + 73728;
    float* wt4 = WT + 368640;
    float* wt5 = WT + 1548288;

    transpose_w<64, 128><<<256,  256, 0, stream>>>(w2, wt2);
    transpose_w<128, 256><<<512, 256, 0, stream>>>(w3, wt3);
    transpose_w<256, 512><<<1024,256, 0, stream>>>(w4, wt4);
    transpose_w<512, 512><<<2048,256, 0, stream>>>(w5, wt5);

    conv1_kernel<<<12544, 256, 0, stream>>>(x, w1, act1);

    // conv2: 64->128, 224->112 : grid = 8b * 2co * 7*7 = 784 (~3 blocks/CU resident)
    conv3x3s2<64, 128, 224, 224, 1, false><<<784, 256, 0, stream>>>(act1, wt2, act2);

    // conv3: 128->256, 112->56 : KSPLIT=2, grid = 8 * 4 * 4*4 * 2 = 1024
    conv3x3s2<128, 256, 112, 112, 2, true><<<1024, 256, 0, stream>>>(act2, wt3, part3);
    reduceN_relu<2><<<25088, 256, 0, stream>>>(part3, act3, 6422528);

    // conv4: 256->512, 56->28 : KSPLIT=4, grid = 8 * 8 * 2*2 * 4 = 1024
    conv3x3s2<256, 512, 56, 56, 4, true><<<1024, 256, 0, stream>>>(act3, wt4, part4);
    reduceN_relu<4><<<12544, 256, 0, stream>>>(part4, act4, 3211264);

    // conv5: 512->512, 28->14 : KSPLIT=16, grid = 8 * 8 * 1 * 16 = 1024
    conv3x3s2<512, 512, 28, 28, 16, true><<<1024, 256, 0, stream>>>(act4, wt5, part5);
    reduceN_relu<16><<<3136, 256, 0, stream>>>(part5, act5, 802816);

    head_kernel<<<392, 256, 0, stream>>>(act5, wh, pred);
    decode_kernel<<<7, 256, 0, stream>>>(pred, out, clsb);
    iou_kernel<<<1201, 256, 0, stream>>>(out, ioub);
    nms_kernel<<<160, 256, 0, stream>>>(clsb, ioub, out);
}

// Round 4
// 1710.543 us; speedup vs baseline: 5.0710x; 5.0710x over previous
//
#include <hip/hip_runtime.h>
#include <hip/hip_bf16.h>
#include <math.h>

// ---------------- problem constants ----------------
#define BATCH 8
#define NCELLS 196          // 14*14
#define NCLS 20
#define HEADC 25            // 1 + 20 + 4

// ---------------- weight transpose: [co][ci][k] -> [ci][k][co] ----------------
template<int CIN, int COUT>
__global__ void transpose_w(const float* __restrict__ w, float* __restrict__ wt) {
    const int n = CIN * COUT * 9;
    for (int i = blockIdx.x * blockDim.x + threadIdx.x; i < n; i += gridDim.x * blockDim.x) {
        int k  = i % 9;
        int ci = (i / 9) % CIN;
        int co = i / (9 * CIN);
        wt[((size_t)ci * 9 + k) * COUT + co] = w[i];
    }
}

// ---------------- conv1: 3->64, 448->224, stride 2, SAME(pad_lo=0,pad_hi=1), ReLU ----------------
__global__ void conv1_kernel(const float* __restrict__ x, const float* __restrict__ w1,
                             float* __restrict__ out) {
    __shared__ float sW[27][64];
    for (int e = threadIdx.x; e < 1728; e += 256) {
        int k = e >> 6, co = e & 63;
        sW[k][co] = w1[co * 27 + k];
    }
    __syncthreads();
    int t = blockIdx.x * 256 + threadIdx.x;     // covers 8*8*224*224 exactly
    int ox  = t % 224;
    int rem = t / 224;
    int oy  = rem % 224;
    rem /= 224;
    int cog = rem & 7;
    int b   = rem >> 3;
    float acc[8] = {0.f,0.f,0.f,0.f,0.f,0.f,0.f,0.f};
    for (int ci = 0; ci < 3; ci++) {
        #pragma unroll
        for (int ky = 0; ky < 3; ky++) {
            int iy = 2 * oy + ky;
            if (iy >= 448) continue;
            #pragma unroll
            for (int kx = 0; kx < 3; kx++) {
                int ix = 2 * ox + kx;
                if (ix >= 448) continue;
                float iv = x[(((size_t)b * 3 + ci) * 448 + iy) * 448 + ix];
                int k = (ci * 3 + ky) * 3 + kx;
                float4 wa = *(const float4*)&sW[k][cog * 8];
                float4 wb = *(const float4*)&sW[k][cog * 8 + 4];
                acc[0] += wa.x * iv; acc[1] += wa.y * iv; acc[2] += wa.z * iv; acc[3] += wa.w * iv;
                acc[4] += wb.x * iv; acc[5] += wb.y * iv; acc[6] += wb.z * iv; acc[7] += wb.w * iv;
            }
        }
    }
    #pragma unroll
    for (int u = 0; u < 8; u++)
        out[(((size_t)b * 64 + cog * 8 + u) * 224 + oy) * 224 + ox] = fmaxf(acc[u], 0.f);
}

// ---------------- generic 3x3 stride-2 SAME conv, tiled, LOW register pressure ----------------
// Block = 512 threads. Tile: 64 co x (16x16) px. Thread = 8co x 4px => 32 accumulators.
// ~60 live VGPRs per thread -> no scratch spill (the R1/R2 killer: GB-scale spill traffic).
// Latency hidden by TLP: 43KB LDS -> 3 blocks/CU = 24 waves/CU.
// R3 bug fixed here: float4 store path must still check ox0 < WOUT (tiles can
// overhang the row when NT*16 > WOUT; unguarded stores corrupted neighbor rows).
template<int CIN, int COUT, int HIN, int WIN, int KSPLIT, bool PARTIAL>
__launch_bounds__(512, 2)
__global__ void conv3x3s2(const float* __restrict__ in, const float* __restrict__ wt,
                          float* __restrict__ out) {
    constexpr int HOUT = HIN / 2, WOUT = WIN / 2;
    constexpr int NT   = (HOUT + 15) / 16;
    constexpr int COCH = COUT / 64;
    constexpr int KC   = 4;
    constexpr int CPS  = CIN / KSPLIT;          // channels per split
    constexpr int NCH  = CPS / KC;              // chunks per block
    constexpr size_t PSZ = (size_t)BATCH * COUT * HOUT * WOUT;

    __shared__ float sIn[KC][33][64];
    __shared__ float sW_[KC * 9 * 64];

    int bid = blockIdx.x;
    int ks  = bid % KSPLIT; bid /= KSPLIT;
    int tx  = bid % NT;     bid /= NT;
    int ty  = bid % NT;     bid /= NT;
    int cch = bid % COCH;
    int b   = bid / COCH;
    int cb  = cch * 64;

    const int tid = threadIdx.x;
    const int cog = tid >> 6;           // 0..7  (uniform per wave -> weight reads broadcast)
    const int pxg = tid & 63;
    const int row = pxg >> 2;           // 0..15
    const int q   = pxg & 3;            // 0..3  (4-px column group)

    float acc[8][4];
    #pragma unroll
    for (int u = 0; u < 8; u++)
        #pragma unroll
        for (int j = 0; j < 4; j++) acc[u][j] = 0.f;

    const float* inb = in + (size_t)(b * CIN + ks * CPS) * HIN * WIN;
    const float* wtb = wt + (size_t)(ks * CPS) * 9 * COUT + cb;

    for (int ch = 0; ch < NCH; ch++) {
        __syncthreads();
        // ---- stage input tile: KC x 33 x 33 (XOR-swizzled 64-float rows) ----
        for (int e = tid; e < KC * 33 * 33; e += 512) {
            int c   = e / 1089;
            int rem = e - c * 1089;
            int liy = rem / 33;
            int lix = rem - liy * 33;
            int iy  = ty * 32 + liy;
            int ix  = tx * 32 + lix;
            float v = 0.f;
            if (iy < HIN && ix < WIN)
                v = inb[(size_t)c * HIN * WIN + iy * WIN + ix];
            int pl = (lix & 3) | ((((lix >> 2) ^ (liy & 15)) << 2));
            sIn[c][liy][pl] = v;
        }
        // ---- stage weights: KC x 9 x 64 ----
        for (int e = tid; e < KC * 9 * 64; e += 512) {
            int c   = e / 576;
            int rem = e - c * 576;
            int k   = rem >> 6;
            int co  = rem & 63;
            sW_[e] = wtb[(size_t)c * 9 * COUT + k * COUT + co];
        }
        __syncthreads();
        // ---- compute ----
        #pragma unroll
        for (int c = 0; c < KC; c++) {
            #pragma unroll
            for (int ky = 0; ky < 3; ky++) {
                int liy = 2 * row + ky;
                int s   = liy & 15;
                float rin[12];
                #pragma unroll
                for (int m = 0; m < 3; m++) {
                    int pb = ((2 * q + m) ^ s) << 2;
                    float4 v = *(const float4*)&sIn[c][liy][pb];
                    rin[4 * m + 0] = v.x; rin[4 * m + 1] = v.y;
                    rin[4 * m + 2] = v.z; rin[4 * m + 3] = v.w;
                }
                #pragma unroll
                for (int kx = 0; kx < 3; kx++) {
                    const float* wp = &sW_[(c * 9 + ky * 3 + kx) * 64 + cog * 8];
                    float wreg[8];
                    *(float4*)&wreg[0] = *(const float4*)wp;
                    *(float4*)&wreg[4] = *(const float4*)(wp + 4);
                    #pragma unroll
                    for (int j = 0; j < 4; j++) {
                        float iv = rin[2 * j + kx];
                        #pragma unroll
                        for (int u = 0; u < 8; u++) acc[u][j] += wreg[u] * iv;
                    }
                }
            }
        }
        inb += KC * HIN * WIN;
        wtb += KC * 9 * COUT;
    }
    // ---- store ----
    int oy  = ty * 16 + row;
    int ox0 = tx * 16 + q * 4;
    float* outp = out + (PARTIAL ? (size_t)ks * PSZ : 0);
    if (oy < HOUT) {
        #pragma unroll
        for (int u = 0; u < 8; u++) {
            size_t rowbase = (((size_t)b * COUT + cb + cog * 8 + u) * HOUT + oy) * WOUT;
            float v[4];
            #pragma unroll
            for (int j = 0; j < 4; j++)
                v[j] = PARTIAL ? acc[u][j] : fmaxf(acc[u][j], 0.f);
            if constexpr (WOUT % 4 == 0) {
                if (ox0 < WOUT)                       // FIX: tile can overhang row
                    *(float4*)&outp[rowbase + ox0] = *(float4*)v;
            } else {
                #pragma unroll
                for (int j = 0; j < 4; j++)
                    if (ox0 + j < WOUT) outp[rowbase + ox0 + j] = v[j];
            }
        }
    }
}

// ---------------- deterministic K-split reduction (+ReLU) ----------------
template<int KS>
__global__ void reduceN_relu(const float* __restrict__ p, float* __restrict__ o, int n) {
    int i = blockIdx.x * 256 + threadIdx.x;
    if (i < n) {
        float s = 0.f;
        #pragma unroll
        for (int k = 0; k < KS; k++) s += p[(size_t)k * n + i];
        o[i] = fmaxf(s, 0.f);
    }
}

// ---------------- 1x1 head: wave per cell, lanes split ci ----------------
__global__ void head_kernel(const float* __restrict__ act, const float* __restrict__ wh,
                            float* __restrict__ pred) {
    int wave = threadIdx.x >> 6;
    int lane = threadIdx.x & 63;
    int cellid = blockIdx.x * 4 + wave;          // 0..1567
    int b = cellid / NCELLS, cell = cellid % NCELLS;
    float acc[HEADC];
    #pragma unroll
    for (int c = 0; c < HEADC; c++) acc[c] = 0.f;
    for (int it = 0; it < 8; it++) {
        int ci = it * 64 + lane;
        float a = act[((size_t)b * 512 + ci) * NCELLS + cell];
        #pragma unroll
        for (int c = 0; c < HEADC; c++) acc[c] += a * wh[c * 512 + ci];
    }
    #pragma unroll
    for (int c = 0; c < HEADC; c++) {
        float v = acc[c];
        v += __shfl_down(v, 32); v += __shfl_down(v, 16); v += __shfl_down(v, 8);
        v += __shfl_down(v, 4);  v += __shfl_down(v, 2);  v += __shfl_down(v, 1);
        if (lane == 0) pred[(size_t)cellid * HEADC + c] = v;
    }
}

// ---------------- decode: sigmoid/softmax/boxes ----------------
__global__ void decode_kernel(const float* __restrict__ pred, float* __restrict__ out,
                              float* __restrict__ cls) {
    int i = blockIdx.x * 256 + threadIdx.x;
    if (i >= BATCH * NCELLS) return;
    const float* p = pred + (size_t)i * HEADC;
    int cell = i % NCELLS;
    int gx = cell % 14, gy = cell / 14;
    float conf = 1.f / (1.f + expf(-p[0]));
    float m = p[1];
    #pragma unroll
    for (int c = 1; c < NCLS; c++) m = fmaxf(m, p[1 + c]);
    float e[NCLS], s = 0.f;
    #pragma unroll
    for (int c = 0; c < NCLS; c++) { e[c] = expf(p[1 + c] - m); s += e[c]; }
    float inv = conf / s;
    #pragma unroll
    for (int c = 0; c < NCLS; c++) cls[(size_t)i * NCLS + c] = e[c] * inv;
    float cx = (1.f / (1.f + expf(-p[21])) + gx) * 32.f;
    float cy = (1.f / (1.f + expf(-p[22])) + gy) * 32.f;
    float w  = expf(p[23]) * 32.f;
    float h  = expf(p[24]) * 32.f;
    float x1 = (cx - 0.5f * w) / 448.f, y1 = (cy - 0.5f * h) / 448.f;
    float x2 = (cx + 0.5f * w) / 448.f, y2 = (cy + 0.5f * h) / 448.f;
    x1 = fminf(fmaxf(x1, 0.f), 1.f); y1 = fminf(fmaxf(y1, 0.f), 1.f);
    x2 = fminf(fmaxf(x2, 0.f), 1.f); y2 = fminf(fmaxf(y2, 0.f), 1.f);
    float* o = out + (size_t)i * 24;
    o[0] = x1; o[1] = y1; o[2] = x2; o[3] = y2;
}

// ---------------- IoU matrices (per batch, 196x196) ----------------
__global__ void iou_kernel(const float* __restrict__ out, float* __restrict__ iou) {
    int idx = blockIdx.x * 256 + threadIdx.x;
    if (idx >= BATCH * NCELLS * NCELLS) return;
    int j = idx % NCELLS;
    int i = (idx / NCELLS) % NCELLS;
    int b = idx / (NCELLS * NCELLS);
    const float* bi = out + (((size_t)b * NCELLS) + i) * 24;
    const float* bj = out + (((size_t)b * NCELLS) + j) * 24;
    float ai = fmaxf(bi[2] - bi[0], 0.f) * fmaxf(bi[3] - bi[1], 0.f);
    float aj = fmaxf(bj[2] - bj[0], 0.f) * fmaxf(bj[3] - bj[1], 0.f);
    float ix1 = fmaxf(bi[0], bj[0]), iy1 = fmaxf(bi[1], bj[1]);
    float ix2 = fminf(bi[2], bj[2]), iy2 = fminf(bi[3], bj[3]);
    float inter = fmaxf(ix2 - ix1, 0.f) * fmaxf(iy2 - iy1, 0.f);
    iou[idx] = inter / (ai + aj - inter + 1e-14f);
}

// ---------------- per-(batch,class) greedy NMS + final score write ----------------
__global__ void nms_kernel(const float* __restrict__ cls, const float* __restrict__ iou,
                           float* __restrict__ out) {
    int b = blockIdx.x / NCLS;
    int c = blockIdx.x % NCLS;
    __shared__ float sc[NCELLS];
    __shared__ float ssort[NCELLS];
    __shared__ int   ord[NCELLS];
    __shared__ int   kp[NCELLS];
    int j = threadIdx.x;
    float sj = 0.f;
    if (j < NCELLS) {
        sj = cls[(((size_t)b * NCELLS) + j) * NCLS + c];
        sc[j] = sj;
    }
    __syncthreads();
    if (j < NCELLS) {
        int r = 0;
        for (int k = 0; k < NCELLS; k++) {
            float sk = sc[k];
            r += (sk > sj) || (sk == sj && k < j);   // stable descending rank
        }
        ord[r] = j; ssort[r] = sj; kp[r] = (sj > 0.01f) ? 1 : 0;
    }
    __syncthreads();
    int myo = (j < NCELLS) ? ord[j] : 0;
    const float* iob = iou + (size_t)b * NCELLS * NCELLS;
    for (int i = 0; i < NCELLS; i++) {
        __syncthreads();
        if (!kp[i]) continue;                        // uniform branch
        if (j > i && j < NCELLS && kp[j]) {
            if (iob[ord[i] * NCELLS + myo] > 0.5f) kp[j] = 0;
        }
    }
    __syncthreads();
    if (j < NCELLS)
        out[(((size_t)b * NCELLS) + ord[j]) * 24 + 4 + c] = kp[j] ? ssort[j] : 0.f;
}

// ---------------- launch ----------------
extern "C" void kernel_launch(void* const* d_in, const int* in_sizes, int n_in,
                              void* d_out, int out_size, void* d_ws, size_t ws_size,
                              hipStream_t stream) {
    const float* x  = (const float*)d_in[0];
    const float* w1 = (const float*)d_in[1];
    const float* w2 = (const float*)d_in[2];
    const float* w3 = (const float*)d_in[3];
    const float* w4 = (const float*)d_in[4];
    const float* w5 = (const float*)d_in[5];
    const float* wh = (const float*)d_in[6];
    float* out = (float*)d_out;
    float* ws  = (float*)d_ws;

    // workspace layout (float offsets)
    float* act1  = ws;                       // 25,690,112  (dead after conv2)
    float* act2  = ws + 25690112;            // 12,845,056  (dead after conv3)
    float* part3 = ws;                       // 2 x 6,422,528  (overlays dead act1)
    float* act3  = ws + 12845056;            // 6,422,528
    float* part4 = ws + 25690112;            // 4 x 3,211,264  (overlays dead act2)
    float* act4  = ws + 19267584;            // 3,211,264
    float* part5 = ws;                       // 16 x 802,816   (overlays dead part3)
    float* act5  = ws + 22478848;            // 802,816
    float* pred  = ws + 23281664;            // 39,200
    float* clsb  = ws + 23320864;            // 31,360
    float* ioub  = ws + 23352224;            // 307,328
    float* WT    = ws + 38535168;            // transposed weights
    float* wt2 = WT;
    float* wt3 = WT + 73728;
    float* wt4 = WT + 368640;
    float* wt5 = WT + 1548288;

    transpose_w<64, 128><<<256,  256, 0, stream>>>(w2, wt2);
    transpose_w<128, 256><<<512, 256, 0, stream>>>(w3, wt3);
    transpose_w<256, 512><<<1024,256, 0, stream>>>(w4, wt4);
    transpose_w<512, 512><<<2048,256, 0, stream>>>(w5, wt5);

    conv1_kernel<<<12544, 256, 0, stream>>>(x, w1, act1);

    // conv2: 64->128, 224->112 : grid = 8b * 2co * 7*7 = 784
    conv3x3s2<64, 128, 224, 224, 1, false><<<784, 512, 0, stream>>>(act1, wt2, act2);

    // conv3: 128->256, 112->56 : KSPLIT=2, grid = 8 * 4 * 4*4 * 2 = 1024
    conv3x3s2<128, 256, 112, 112, 2, true><<<1024, 512, 0, stream>>>(act2, wt3, part3);
    reduceN_relu<2><<<25088, 256, 0, stream>>>(part3, act3, 6422528);

    // conv4: 256->512, 56->28 : KSPLIT=4, grid = 8 * 8 * 2*2 * 4 = 1024
    conv3x3s2<256, 512, 56, 56, 4, true><<<1024, 512, 0, stream>>>(act3, wt4, part4);
    reduceN_relu<4><<<12544, 256, 0, stream>>>(part4, act4, 3211264);

    // conv5: 512->512, 28->14 : KSPLIT=16, grid = 8 * 8 * 1 * 16 = 1024
    conv3x3s2<512, 512, 28, 28, 16, true><<<1024, 512, 0, stream>>>(act4, wt5, part5);
    reduceN_relu<16><<<3136, 256, 0, stream>>>(part5, act5, 802816);

    head_kernel<<<392, 256, 0, stream>>>(act5, wh, pred);
    decode_kernel<<<7, 256, 0, stream>>>(pred, out, clsb);
    iou_kernel<<<1201, 256, 0, stream>>>(out, ioub);
    nms_kernel<<<160, 256, 0, stream>>>(clsb, ioub, out);
}

// Round 5
// 577.279 us; speedup vs baseline: 15.0259x; 2.9631x over previous
//
#include <hip/hip_runtime.h>
#include <math.h>

#define BATCH 8
#define NCELLS 196
#define NCLS 20
#define HEADC 25

typedef __attribute__((ext_vector_type(8))) short short8;
typedef __attribute__((ext_vector_type(4))) float f32x4;
#define MFMA16(a,b,c) __builtin_amdgcn_mfma_f32_16x16x32_bf16(a,b,c,0,0,0)

// ---- bf16 split helpers (RNE via bit ops; deterministic) ----
__device__ __forceinline__ unsigned short f2bf(float x) {
    union { float f; unsigned u; } a; a.f = x;
    unsigned r = a.u + 0x7FFFu + ((a.u >> 16) & 1u);
    return (unsigned short)(r >> 16);
}
__device__ __forceinline__ float bf2f(unsigned short h) {
    union { unsigned u; float f; } a; a.u = ((unsigned)h) << 16;
    return a.f;
}
__device__ __forceinline__ void split_bf(float x, unsigned short& h, unsigned short& l) {
    h = f2bf(x);
    l = f2bf(x - bf2f(h));
}

// ---- weight prep: w[co][ci][3][3] fp32 -> MFMA-A-fragment-ordered hi/lo bf16 ----
// element idx = ((plane*CH + chunk)*G + g)*512 + lane*8 + j
//   co = g*16 + (lane&15), ci = chunk*32 + (lane>>4)*8 + j, plane = ky*3+kx
template<int CIN, int COUT>
__global__ void prep_w(const float* __restrict__ w, unsigned short* __restrict__ whi,
                       unsigned short* __restrict__ wlo) {
    constexpr int G = COUT / 16, CH = CIN / 32;
    int idx = blockIdx.x * 256 + threadIdx.x;
    if (idx >= 9 * CIN * COUT) return;
    int j    = idx & 7;
    int lane = (idx >> 3) & 63;
    int fg   = idx >> 9;
    int g    = fg % G;
    int fc   = fg / G;
    int chunk = fc % CH;
    int plane = fc / CH;
    int m = lane & 15, quad = lane >> 4;
    int co = g * 16 + m;
    int ci = chunk * 32 + quad * 8 + j;
    int ky = plane / 3, kx = plane % 3;
    float v = w[((co * CIN + ci) * 3 + ky) * 3 + kx];
    unsigned short h, l; split_bf(v, h, l);
    whi[idx] = h; wlo[idx] = l;
}

// ---- conv1: 3->64, 448->224, fp32 compute, outputs NHWC bf16 hi/lo ----
__global__ void conv1_kernel(const float* __restrict__ x, const float* __restrict__ w1,
                             unsigned short* __restrict__ ohi, unsigned short* __restrict__ olo) {
    __shared__ float sW[27][64];
    for (int e = threadIdx.x; e < 1728; e += 256) {
        int k = e >> 6, co = e & 63;
        sW[k][co] = w1[co * 27 + k];
    }
    __syncthreads();
    int t = blockIdx.x * 256 + threadIdx.x;
    int ox  = t % 224;
    int rem = t / 224;
    int oy  = rem % 224;
    rem /= 224;
    int cog = rem & 7;
    int b   = rem >> 3;
    float acc[8] = {0.f,0.f,0.f,0.f,0.f,0.f,0.f,0.f};
    for (int ci = 0; ci < 3; ci++) {
        #pragma unroll
        for (int ky = 0; ky < 3; ky++) {
            int iy = 2 * oy + ky;
            if (iy >= 448) continue;
            #pragma unroll
            for (int kx = 0; kx < 3; kx++) {
                int ix = 2 * ox + kx;
                if (ix >= 448) continue;
                float iv = x[(((size_t)b * 3 + ci) * 448 + iy) * 448 + ix];
                int k = (ci * 3 + ky) * 3 + kx;
                float4 wa = *(const float4*)&sW[k][cog * 8];
                float4 wb = *(const float4*)&sW[k][cog * 8 + 4];
                acc[0] += wa.x * iv; acc[1] += wa.y * iv; acc[2] += wa.z * iv; acc[3] += wa.w * iv;
                acc[4] += wb.x * iv; acc[5] += wb.y * iv; acc[6] += wb.z * iv; acc[7] += wb.w * iv;
            }
        }
    }
    union { unsigned short u[8]; uint4 v; } ph, pl;
    #pragma unroll
    for (int u = 0; u < 8; u++) {
        float v = fmaxf(acc[u], 0.f);
        split_bf(v, ph.u[u], pl.u[u]);
    }
    size_t base = ((size_t)(b * 224 + oy) * 224 + ox) * 64 + cog * 8;
    *(uint4*)&ohi[base] = ph.v;
    *(uint4*)&olo[base] = pl.v;
}

// ---- MFMA conv: 3x3 stride2 SAME, NHWC bf16 hi/lo in, NHWC hi/lo out (or fp32 partial) ----
// Block 256 thr = 4 waves; tile 128co x (8y x 8x px). Wave = 32co x 64px.
// MFMA 16x16x32: A[m=lane&15][k=quad*8+j] (weights, frag-preordered in global),
// B[k=quad*8+j][n=lane&15] (acts from LDS, ci-contiguous), D col=lane&15 row=quad*4+reg.
template<int CIN, int COUT, int HIN, int WIN, int KSPLIT, bool PARTIAL>
__launch_bounds__(256, 3)
__global__ void conv_mfma(const unsigned short* __restrict__ ahi, const unsigned short* __restrict__ alo,
                          const unsigned short* __restrict__ whi, const unsigned short* __restrict__ wlo,
                          unsigned short* __restrict__ ohi, unsigned short* __restrict__ olo,
                          float* __restrict__ part) {
    constexpr int HOUT = HIN / 2, WOUT = WIN / 2;
    constexpr int TX = (WOUT + 7) / 8, TY = (HOUT + 7) / 8;
    constexpr int COG = COUT / 128;
    constexpr int CH_TOT = CIN / 32;
    constexpr int CH = CH_TOT / KSPLIT;
    constexpr int G = COUT / 16;
    constexpr int PLANE = 17 * 17 * 36;          // ushort units per hi/lo plane (72B px slots)
    constexpr size_t PSZ = (size_t)BATCH * HOUT * WOUT * COUT;

    __shared__ __align__(16) unsigned short sA[2 * PLANE];   // 41.6 KB

    int bid = blockIdx.x;
    int ks  = bid % KSPLIT; bid /= KSPLIT;
    int txi = bid % TX;     bid /= TX;
    int tyi = bid % TY;     bid /= TY;
    int cg  = bid % COG;
    int b   = bid / COG;
    int oy0 = tyi * 8, ox0 = txi * 8;
    int iy0 = oy0 * 2, ix0 = ox0 * 2;

    int tid = threadIdx.x;
    int w   = tid >> 6;
    int lane = tid & 63;
    int n = lane & 15, quad = lane >> 4;

    int oyl[4], oxl[4], boff[4];
    #pragma unroll
    for (int nt = 0; nt < 4; nt++) {
        int oyq = nt >> 1, oxq = nt & 1;
        int oy_off = oyq * 4 + (n >> 2);
        int ox_off = oxq * 4 + (n & 3);
        oyl[nt] = oy0 + oy_off;
        oxl[nt] = ox0 + ox_off;
        boff[nt] = (2 * oy_off * 17 + 2 * ox_off) * 36 + quad * 8;
    }

    f32x4 zero = {0.f, 0.f, 0.f, 0.f};
    f32x4 acc[2][4];
    #pragma unroll
    for (int ct = 0; ct < 2; ct++)
        #pragma unroll
        for (int nt = 0; nt < 4; nt++) acc[ct][nt] = zero;

    int g0 = cg * 8 + w * 2;        // wave's first co-16-group

    for (int ch = 0; ch < CH; ch++) {
        int chunk = ks * CH + ch;
        int ci0 = chunk * 32;
        __syncthreads();
        // ---- stage act tile: 17x17 px x 32 ci, hi+lo ----
        for (int e = tid; e < 17 * 17 * 8; e += 256) {
            int pxi = e >> 3, grp = e & 7;
            int liy = pxi / 17, lix = pxi - liy * 17;
            int iy = iy0 + liy, ix = ix0 + lix;
            uint4 v = make_uint4(0u, 0u, 0u, 0u);
            if (iy < HIN && ix < WIN) {
                const unsigned short* src = (grp < 4 ? ahi : alo)
                    + ((size_t)(b * HIN + iy) * WIN + ix) * CIN + ci0 + (grp & 3) * 8;
                v = *(const uint4*)src;
            }
            *(uint4*)&sA[(grp >> 2) * PLANE + pxi * 36 + (grp & 3) * 8] = v;
        }
        __syncthreads();
        // ---- 9 kernel planes ----
        #pragma unroll
        for (int pl = 0; pl < 9; pl++) {
            int ky = pl / 3, kx = pl % 3;
            size_t fbase = ((size_t)(pl * CH_TOT + chunk) * G + g0) * 512 + lane * 8;
            short8 Ah0 = *(const short8*)(whi + fbase);
            short8 Ah1 = *(const short8*)(whi + fbase + 512);
            short8 Al0 = *(const short8*)(wlo + fbase);
            short8 Al1 = *(const short8*)(wlo + fbase + 512);
            int koff = (ky * 17 + kx) * 36;
            #pragma unroll
            for (int nt = 0; nt < 4; nt++) {
                short8 Bh = *(const short8*)&sA[boff[nt] + koff];
                short8 Bl = *(const short8*)&sA[PLANE + boff[nt] + koff];
                acc[0][nt] = MFMA16(Ah0, Bh, acc[0][nt]);
                acc[0][nt] = MFMA16(Ah0, Bl, acc[0][nt]);
                acc[0][nt] = MFMA16(Al0, Bh, acc[0][nt]);
                acc[1][nt] = MFMA16(Ah1, Bh, acc[1][nt]);
                acc[1][nt] = MFMA16(Ah1, Bl, acc[1][nt]);
                acc[1][nt] = MFMA16(Al1, Bh, acc[1][nt]);
            }
        }
    }
    // ---- epilogue ----
    int cob = cg * 128 + w * 32;
    #pragma unroll
    for (int ct = 0; ct < 2; ct++) {
        #pragma unroll
        for (int nt = 0; nt < 4; nt++) {
            if (oyl[nt] >= HOUT || oxl[nt] >= WOUT) continue;
            size_t base = ((size_t)(b * HOUT + oyl[nt]) * WOUT + oxl[nt]) * COUT
                          + cob + ct * 16 + quad * 4;
            if (PARTIAL) {
                *(f32x4*)&part[(size_t)ks * PSZ + base] = acc[ct][nt];
            } else {
                unsigned long long h64 = 0ull, l64 = 0ull;
                #pragma unroll
                for (int r = 0; r < 4; r++) {
                    float v = fmaxf(acc[ct][nt][r], 0.f);
                    unsigned short hh, ll; split_bf(v, hh, ll);
                    h64 |= ((unsigned long long)hh) << (16 * r);
                    l64 |= ((unsigned long long)ll) << (16 * r);
                }
                *(unsigned long long*)&ohi[base] = h64;
                *(unsigned long long*)&olo[base] = l64;
            }
        }
    }
}

// ---- reduce 4 K-split partials (fp32) -> ReLU -> hi/lo bf16 ----
__global__ void reduce4_split(const float* __restrict__ p, unsigned short* __restrict__ oh,
                              unsigned short* __restrict__ ol) {
    const int N4 = 802816 / 4;
    int i = blockIdx.x * 256 + threadIdx.x;
    if (i >= N4) return;
    const float4* p4 = (const float4*)p;
    float4 s = p4[i];
    #pragma unroll
    for (int k = 1; k < 4; k++) {
        float4 t = p4[i + k * N4];
        s.x += t.x; s.y += t.y; s.z += t.z; s.w += t.w;
    }
    float v[4] = { fmaxf(s.x,0.f), fmaxf(s.y,0.f), fmaxf(s.z,0.f), fmaxf(s.w,0.f) };
    unsigned long long h64 = 0ull, l64 = 0ull;
    #pragma unroll
    for (int r = 0; r < 4; r++) {
        unsigned short hh, ll; split_bf(v[r], hh, ll);
        h64 |= ((unsigned long long)hh) << (16 * r);
        l64 |= ((unsigned long long)ll) << (16 * r);
    }
    *(unsigned long long*)&oh[i * 4] = h64;
    *(unsigned long long*)&ol[i * 4] = l64;
}

// ---- 1x1 head: wave per cell; act5 NHWC hi/lo ----
__global__ void head_kernel(const unsigned short* __restrict__ ah, const unsigned short* __restrict__ al,
                            const float* __restrict__ wh, float* __restrict__ pred) {
    int wave = threadIdx.x >> 6;
    int lane = threadIdx.x & 63;
    int cellid = blockIdx.x * 4 + wave;
    float acc[HEADC];
    #pragma unroll
    for (int c = 0; c < HEADC; c++) acc[c] = 0.f;
    for (int it = 0; it < 8; it++) {
        int ci = it * 64 + lane;
        size_t idx = (size_t)cellid * 512 + ci;
        float a = bf2f(ah[idx]) + bf2f(al[idx]);
        #pragma unroll
        for (int c = 0; c < HEADC; c++) acc[c] += a * wh[c * 512 + ci];
    }
    #pragma unroll
    for (int c = 0; c < HEADC; c++) {
        float v = acc[c];
        v += __shfl_down(v, 32); v += __shfl_down(v, 16); v += __shfl_down(v, 8);
        v += __shfl_down(v, 4);  v += __shfl_down(v, 2);  v += __shfl_down(v, 1);
        if (lane == 0) pred[(size_t)cellid * HEADC + c] = v;
    }
}

// ---- decode ----
__global__ void decode_kernel(const float* __restrict__ pred, float* __restrict__ out,
                              float* __restrict__ cls) {
    int i = blockIdx.x * 256 + threadIdx.x;
    if (i >= BATCH * NCELLS) return;
    const float* p = pred + (size_t)i * HEADC;
    int cell = i % NCELLS;
    int gx = cell % 14, gy = cell / 14;
    float conf = 1.f / (1.f + expf(-p[0]));
    float m = p[1];
    #pragma unroll
    for (int c = 1; c < NCLS; c++) m = fmaxf(m, p[1 + c]);
    float e[NCLS], s = 0.f;
    #pragma unroll
    for (int c = 0; c < NCLS; c++) { e[c] = expf(p[1 + c] - m); s += e[c]; }
    float inv = conf / s;
    #pragma unroll
    for (int c = 0; c < NCLS; c++) cls[(size_t)i * NCLS + c] = e[c] * inv;
    float cx = (1.f / (1.f + expf(-p[21])) + gx) * 32.f;
    float cy = (1.f / (1.f + expf(-p[22])) + gy) * 32.f;
    float w  = expf(p[23]) * 32.f;
    float h  = expf(p[24]) * 32.f;
    float x1 = (cx - 0.5f * w) / 448.f, y1 = (cy - 0.5f * h) / 448.f;
    float x2 = (cx + 0.5f * w) / 448.f, y2 = (cy + 0.5f * h) / 448.f;
    x1 = fminf(fmaxf(x1, 0.f), 1.f); y1 = fminf(fmaxf(y1, 0.f), 1.f);
    x2 = fminf(fmaxf(x2, 0.f), 1.f); y2 = fminf(fmaxf(y2, 0.f), 1.f);
    float* o = out + (size_t)i * 24;
    o[0] = x1; o[1] = y1; o[2] = x2; o[3] = y2;
}

// ---- IoU ----
__global__ void iou_kernel(const float* __restrict__ out, float* __restrict__ iou) {
    int idx = blockIdx.x * 256 + threadIdx.x;
    if (idx >= BATCH * NCELLS * NCELLS) return;
    int j = idx % NCELLS;
    int i = (idx / NCELLS) % NCELLS;
    int b = idx / (NCELLS * NCELLS);
    const float* bi = out + (((size_t)b * NCELLS) + i) * 24;
    const float* bj = out + (((size_t)b * NCELLS) + j) * 24;
    float ai = fmaxf(bi[2] - bi[0], 0.f) * fmaxf(bi[3] - bi[1], 0.f);
    float aj = fmaxf(bj[2] - bj[0], 0.f) * fmaxf(bj[3] - bj[1], 0.f);
    float ix1 = fmaxf(bi[0], bj[0]), iy1 = fmaxf(bi[1], bj[1]);
    float ix2 = fminf(bi[2], bj[2]), iy2 = fminf(bi[3], bj[3]);
    float inter = fmaxf(ix2 - ix1, 0.f) * fmaxf(iy2 - iy1, 0.f);
    iou[idx] = inter / (ai + aj - inter + 1e-14f);
}

// ---- NMS ----
__global__ void nms_kernel(const float* __restrict__ cls, const float* __restrict__ iou,
                           float* __restrict__ out) {
    int b = blockIdx.x / NCLS;
    int c = blockIdx.x % NCLS;
    __shared__ float sc[NCELLS];
    __shared__ float ssort[NCELLS];
    __shared__ int   ord[NCELLS];
    __shared__ int   kp[NCELLS];
    int j = threadIdx.x;
    float sj = 0.f;
    if (j < NCELLS) {
        sj = cls[(((size_t)b * NCELLS) + j) * NCLS + c];
        sc[j] = sj;
    }
    __syncthreads();
    if (j < NCELLS) {
        int r = 0;
        for (int k = 0; k < NCELLS; k++) {
            float sk = sc[k];
            r += (sk > sj) || (sk == sj && k < j);
        }
        ord[r] = j; ssort[r] = sj; kp[r] = (sj > 0.01f) ? 1 : 0;
    }
    __syncthreads();
    int myo = (j < NCELLS) ? ord[j] : 0;
    const float* iob = iou + (size_t)b * NCELLS * NCELLS;
    for (int i = 0; i < NCELLS; i++) {
        __syncthreads();
        if (!kp[i]) continue;
        if (j > i && j < NCELLS && kp[j]) {
            if (iob[ord[i] * NCELLS + myo] > 0.5f) kp[j] = 0;
        }
    }
    __syncthreads();
    if (j < NCELLS)
        out[(((size_t)b * NCELLS) + ord[j]) * 24 + 4 + c] = kp[j] ? ssort[j] : 0.f;
}

// ---- launch ----
extern "C" void kernel_launch(void* const* d_in, const int* in_sizes, int n_in,
                              void* d_out, int out_size, void* d_ws, size_t ws_size,
                              hipStream_t stream) {
    const float* x  = (const float*)d_in[0];
    const float* w1 = (const float*)d_in[1];
    const float* w2 = (const float*)d_in[2];
    const float* w3 = (const float*)d_in[3];
    const float* w4 = (const float*)d_in[4];
    const float* w5 = (const float*)d_in[5];
    const float* wh = (const float*)d_in[6];
    float* out = (float*)d_out;
    char* base = (char*)d_ws;

    // region A (0 .. 102,760,448)
    unsigned short* a1h = (unsigned short*)(base);
    unsigned short* a1l = a1h + 25690112;
    // overlays in A after act1 dead:
    unsigned short* a3h = (unsigned short*)(base);
    unsigned short* a3l = a3h + 6422528;
    float*          part5 = (float*)(base);                    // 12,845,056 B
    unsigned short* a5h = (unsigned short*)(base + 12845056);
    unsigned short* a5l = a5h + 802816;
    float* pred = (float*)(base + 16056320);
    float* clsb = (float*)(base + 16213120);
    float* ioub = (float*)(base + 16338560);
    // region B (102,760,448 .. 154,140,672)
    unsigned short* a2h = (unsigned short*)(base + 102760448);
    unsigned short* a2l = a2h + 12845056;
    unsigned short* a4h = (unsigned short*)(base + 102760448);
    unsigned short* a4l = a4h + 3211264;
    // weights (154,140,672 .. 169,771,008)
    unsigned short* w2h = (unsigned short*)(base + 154140672);
    unsigned short* w3h = w2h + 73728;
    unsigned short* w4h = w3h + 294912;
    unsigned short* w5h = w4h + 1179648;
    unsigned short* w2l = (unsigned short*)(base + 161955840);
    unsigned short* w3l = w2l + 73728;
    unsigned short* w4l = w3l + 294912;
    unsigned short* w5l = w4l + 1179648;

    prep_w<64, 128> <<<288,  256, 0, stream>>>(w2, w2h, w2l);
    prep_w<128, 256><<<1152, 256, 0, stream>>>(w3, w3h, w3l);
    prep_w<256, 512><<<4608, 256, 0, stream>>>(w4, w4h, w4l);
    prep_w<512, 512><<<9216, 256, 0, stream>>>(w5, w5h, w5l);

    conv1_kernel<<<12544, 256, 0, stream>>>(x, w1, a1h, a1l);

    // conv2: 64->128, 224->112 : 8b * 14*14 tiles * 1 cog = 1568
    conv_mfma<64, 128, 224, 224, 1, false><<<1568, 256, 0, stream>>>(
        a1h, a1l, w2h, w2l, a2h, a2l, nullptr);
    // conv3: 128->256, 112->56 : 8 * 7*7 * 2 = 784
    conv_mfma<128, 256, 112, 112, 1, false><<<784, 256, 0, stream>>>(
        a2h, a2l, w3h, w3l, a3h, a3l, nullptr);
    // conv4: 256->512, 56->28 : 8 * 4*4 * 4 = 512
    conv_mfma<256, 512, 56, 56, 1, false><<<512, 256, 0, stream>>>(
        a3h, a3l, w4h, w4l, a4h, a4l, nullptr);
    // conv5: 512->512, 28->14 : 8 * 2*2 * 4 * KS4 = 512
    conv_mfma<512, 512, 28, 28, 4, true><<<512, 256, 0, stream>>>(
        a4h, a4l, w5h, w5l, nullptr, nullptr, part5);
    reduce4_split<<<784, 256, 0, stream>>>(part5, a5h, a5l);

    head_kernel<<<392, 256, 0, stream>>>(a5h, a5l, wh, pred);
    decode_kernel<<<7, 256, 0, stream>>>(pred, out, clsb);
    iou_kernel<<<1201, 256, 0, stream>>>(out, ioub);
    nms_kernel<<<160, 256, 0, stream>>>(clsb, ioub, out);
}

// Round 6
// 516.145 us; speedup vs baseline: 16.8056x; 1.1184x over previous
//
#include <hip/hip_runtime.h>
#include <math.h>

#define BATCH 8
#define NCELLS 196
#define NCLS 20
#define HEADC 25

typedef __attribute__((ext_vector_type(8))) short short8;
typedef __attribute__((ext_vector_type(4))) float f32x4;
#define MFMA16(a,b,c) __builtin_amdgcn_mfma_f32_16x16x32_bf16(a,b,c,0,0,0)

// ---- bf16 split helpers (RNE via bit ops; deterministic) ----
__device__ __forceinline__ unsigned short f2bf(float x) {
    union { float f; unsigned u; } a; a.f = x;
    unsigned r = a.u + 0x7FFFu + ((a.u >> 16) & 1u);
    return (unsigned short)(r >> 16);
}
__device__ __forceinline__ float bf2f(unsigned short h) {
    union { unsigned u; float f; } a; a.u = ((unsigned)h) << 16;
    return a.f;
}
__device__ __forceinline__ void split_bf(float x, unsigned short& h, unsigned short& l) {
    h = f2bf(x);
    l = f2bf(x - bf2f(h));
}

// ---- weight prep: w[co][ci][3][3] fp32 -> MFMA-A-fragment-ordered hi/lo bf16 ----
template<int CIN, int COUT>
__global__ void prep_w(const float* __restrict__ w, unsigned short* __restrict__ whi,
                       unsigned short* __restrict__ wlo) {
    constexpr int G = COUT / 16, CH = CIN / 32;
    int idx = blockIdx.x * 256 + threadIdx.x;
    if (idx >= 9 * CIN * COUT) return;
    int j    = idx & 7;
    int lane = (idx >> 3) & 63;
    int fg   = idx >> 9;
    int g    = fg % G;
    int fc   = fg / G;
    int chunk = fc % CH;
    int plane = fc / CH;
    int m = lane & 15, quad = lane >> 4;
    int co = g * 16 + m;
    int ci = chunk * 32 + quad * 8 + j;
    int ky = plane / 3, kx = plane % 3;
    float v = w[((co * CIN + ci) * 3 + ky) * 3 + kx];
    unsigned short h, l; split_bf(v, h, l);
    whi[idx] = h; wlo[idx] = l;
}

// ---- conv1: 3->64, 448->224, fp32 compute, COALESCED NHWC hi/lo stores ----
// Block = 256 thr = 32 output px (one row segment) x 8 ch-groups; tid = pxl*8+cog
// so a wave's stores are contiguous 1KB runs per buffer (kills the 2.9x RMW
// write amplification seen in R5: WRITE 300MB vs 103MB ideal).
__global__ void conv1_kernel(const float* __restrict__ x, const float* __restrict__ w1,
                             unsigned short* __restrict__ ohi, unsigned short* __restrict__ olo) {
    __shared__ float sW[27][64];
    __shared__ float sX[3][3][66];    // ci, ky, 65 input cols (+pad)
    int bid = blockIdx.x;
    int xseg = bid % 7;  bid /= 7;
    int oy   = bid % 224;
    int b    = bid / 224;
    int ox0  = xseg * 32;

    for (int e = threadIdx.x; e < 1728; e += 256) {
        int k = e >> 6, co = e & 63;
        sW[k][co] = w1[co * 27 + k];
    }
    for (int e = threadIdx.x; e < 594; e += 256) {
        int ci = e / 198;
        int r  = e - ci * 198;
        int ky = r / 66;
        int lx = r - ky * 66;
        int iy = 2 * oy + ky;
        int ix = 2 * ox0 + lx;
        float v = 0.f;
        if (lx < 65 && iy < 448 && ix < 448)
            v = x[(((size_t)b * 3 + ci) * 448 + iy) * 448 + ix];
        sX[ci][ky][lx] = v;
    }
    __syncthreads();

    int pxl = threadIdx.x >> 3;       // 0..31
    int cog = threadIdx.x & 7;        // 0..7
    float acc[8] = {0.f,0.f,0.f,0.f,0.f,0.f,0.f,0.f};
    #pragma unroll
    for (int ci = 0; ci < 3; ci++) {
        #pragma unroll
        for (int ky = 0; ky < 3; ky++) {
            const float* row = sX[ci][ky];
            #pragma unroll
            for (int kx = 0; kx < 3; kx++) {
                float iv = row[2 * pxl + kx];
                int k = (ci * 3 + ky) * 3 + kx;
                float4 wa = *(const float4*)&sW[k][cog * 8];
                float4 wb = *(const float4*)&sW[k][cog * 8 + 4];
                acc[0] += wa.x * iv; acc[1] += wa.y * iv; acc[2] += wa.z * iv; acc[3] += wa.w * iv;
                acc[4] += wb.x * iv; acc[5] += wb.y * iv; acc[6] += wb.z * iv; acc[7] += wb.w * iv;
            }
        }
    }
    union { unsigned short u[8]; uint4 v; } ph, pl;
    #pragma unroll
    for (int u = 0; u < 8; u++) {
        float v = fmaxf(acc[u], 0.f);
        split_bf(v, ph.u[u], pl.u[u]);
    }
    size_t base = ((size_t)(b * 224 + oy) * 224 + ox0 + pxl) * 64 + cog * 8;
    *(uint4*)&ohi[base] = ph.v;
    *(uint4*)&olo[base] = pl.v;
}

// ---- MFMA conv: 3x3 stride2 SAME, NHWC bf16 hi/lo in, NHWC hi/lo out (or fp32 partial) ----
template<int CIN, int COUT, int HIN, int WIN, int KSPLIT, bool PARTIAL>
__launch_bounds__(256, 3)
__global__ void conv_mfma(const unsigned short* __restrict__ ahi, const unsigned short* __restrict__ alo,
                          const unsigned short* __restrict__ whi, const unsigned short* __restrict__ wlo,
                          unsigned short* __restrict__ ohi, unsigned short* __restrict__ olo,
                          float* __restrict__ part) {
    constexpr int HOUT = HIN / 2, WOUT = WIN / 2;
    constexpr int TX = (WOUT + 7) / 8, TY = (HOUT + 7) / 8;
    constexpr int COG = COUT / 128;
    constexpr int CH_TOT = CIN / 32;
    constexpr int CH = CH_TOT / KSPLIT;
    constexpr int G = COUT / 16;
    constexpr int PLANE = 17 * 17 * 36;
    constexpr size_t PSZ = (size_t)BATCH * HOUT * WOUT * COUT;

    __shared__ __align__(16) unsigned short sA[2 * PLANE];

    int bid = blockIdx.x;
    int ks  = bid % KSPLIT; bid /= KSPLIT;
    int txi = bid % TX;     bid /= TX;
    int tyi = bid % TY;     bid /= TY;
    int cg  = bid % COG;
    int b   = bid / COG;
    int oy0 = tyi * 8, ox0 = txi * 8;
    int iy0 = oy0 * 2, ix0 = ox0 * 2;

    int tid = threadIdx.x;
    int w   = tid >> 6;
    int lane = tid & 63;
    int n = lane & 15, quad = lane >> 4;

    int oyl[4], oxl[4], boff[4];
    #pragma unroll
    for (int nt = 0; nt < 4; nt++) {
        int oyq = nt >> 1, oxq = nt & 1;
        int oy_off = oyq * 4 + (n >> 2);
        int ox_off = oxq * 4 + (n & 3);
        oyl[nt] = oy0 + oy_off;
        oxl[nt] = ox0 + ox_off;
        boff[nt] = (2 * oy_off * 17 + 2 * ox_off) * 36 + quad * 8;
    }

    f32x4 zero = {0.f, 0.f, 0.f, 0.f};
    f32x4 acc[2][4];
    #pragma unroll
    for (int ct = 0; ct < 2; ct++)
        #pragma unroll
        for (int nt = 0; nt < 4; nt++) acc[ct][nt] = zero;

    int g0 = cg * 8 + w * 2;

    for (int ch = 0; ch < CH; ch++) {
        int chunk = ks * CH + ch;
        int ci0 = chunk * 32;
        __syncthreads();
        for (int e = tid; e < 17 * 17 * 8; e += 256) {
            int pxi = e >> 3, grp = e & 7;
            int liy = pxi / 17, lix = pxi - liy * 17;
            int iy = iy0 + liy, ix = ix0 + lix;
            uint4 v = make_uint4(0u, 0u, 0u, 0u);
            if (iy < HIN && ix < WIN) {
                const unsigned short* src = (grp < 4 ? ahi : alo)
                    + ((size_t)(b * HIN + iy) * WIN + ix) * CIN + ci0 + (grp & 3) * 8;
                v = *(const uint4*)src;
            }
            *(uint4*)&sA[(grp >> 2) * PLANE + pxi * 36 + (grp & 3) * 8] = v;
        }
        __syncthreads();
        #pragma unroll
        for (int pl = 0; pl < 9; pl++) {
            int ky = pl / 3, kx = pl % 3;
            size_t fbase = ((size_t)(pl * CH_TOT + chunk) * G + g0) * 512 + lane * 8;
            short8 Ah0 = *(const short8*)(whi + fbase);
            short8 Ah1 = *(const short8*)(whi + fbase + 512);
            short8 Al0 = *(const short8*)(wlo + fbase);
            short8 Al1 = *(const short8*)(wlo + fbase + 512);
            int koff = (ky * 17 + kx) * 36;
            #pragma unroll
            for (int nt = 0; nt < 4; nt++) {
                short8 Bh = *(const short8*)&sA[boff[nt] + koff];
                short8 Bl = *(const short8*)&sA[PLANE + boff[nt] + koff];
                acc[0][nt] = MFMA16(Ah0, Bh, acc[0][nt]);
                acc[0][nt] = MFMA16(Ah0, Bl, acc[0][nt]);
                acc[0][nt] = MFMA16(Al0, Bh, acc[0][nt]);
                acc[1][nt] = MFMA16(Ah1, Bh, acc[1][nt]);
                acc[1][nt] = MFMA16(Ah1, Bl, acc[1][nt]);
                acc[1][nt] = MFMA16(Al1, Bh, acc[1][nt]);
            }
        }
    }
    int cob = cg * 128 + w * 32;
    #pragma unroll
    for (int ct = 0; ct < 2; ct++) {
        #pragma unroll
        for (int nt = 0; nt < 4; nt++) {
            if (oyl[nt] >= HOUT || oxl[nt] >= WOUT) continue;
            size_t base = ((size_t)(b * HOUT + oyl[nt]) * WOUT + oxl[nt]) * COUT
                          + cob + ct * 16 + quad * 4;
            if (PARTIAL) {
                *(f32x4*)&part[(size_t)ks * PSZ + base] = acc[ct][nt];
            } else {
                unsigned long long h64 = 0ull, l64 = 0ull;
                #pragma unroll
                for (int r = 0; r < 4; r++) {
                    float v = fmaxf(acc[ct][nt][r], 0.f);
                    unsigned short hh, ll; split_bf(v, hh, ll);
                    h64 |= ((unsigned long long)hh) << (16 * r);
                    l64 |= ((unsigned long long)ll) << (16 * r);
                }
                *(unsigned long long*)&ohi[base] = h64;
                *(unsigned long long*)&olo[base] = l64;
            }
        }
    }
}

// ---- reduce 4 K-split partials (fp32) -> ReLU -> hi/lo bf16 ----
__global__ void reduce4_split(const float* __restrict__ p, unsigned short* __restrict__ oh,
                              unsigned short* __restrict__ ol) {
    const int N4 = 802816 / 4;
    int i = blockIdx.x * 256 + threadIdx.x;
    if (i >= N4) return;
    const float4* p4 = (const float4*)p;
    float4 s = p4[i];
    #pragma unroll
    for (int k = 1; k < 4; k++) {
        float4 t = p4[i + k * N4];
        s.x += t.x; s.y += t.y; s.z += t.z; s.w += t.w;
    }
    float v[4] = { fmaxf(s.x,0.f), fmaxf(s.y,0.f), fmaxf(s.z,0.f), fmaxf(s.w,0.f) };
    unsigned long long h64 = 0ull, l64 = 0ull;
    #pragma unroll
    for (int r = 0; r < 4; r++) {
        unsigned short hh, ll; split_bf(v[r], hh, ll);
        h64 |= ((unsigned long long)hh) << (16 * r);
        l64 |= ((unsigned long long)ll) << (16 * r);
    }
    *(unsigned long long*)&oh[i * 4] = h64;
    *(unsigned long long*)&ol[i * 4] = l64;
}

// ---- 1x1 head ----
__global__ void head_kernel(const unsigned short* __restrict__ ah, const unsigned short* __restrict__ al,
                            const float* __restrict__ wh, float* __restrict__ pred) {
    int wave = threadIdx.x >> 6;
    int lane = threadIdx.x & 63;
    int cellid = blockIdx.x * 4 + wave;
    float acc[HEADC];
    #pragma unroll
    for (int c = 0; c < HEADC; c++) acc[c] = 0.f;
    for (int it = 0; it < 8; it++) {
        int ci = it * 64 + lane;
        size_t idx = (size_t)cellid * 512 + ci;
        float a = bf2f(ah[idx]) + bf2f(al[idx]);
        #pragma unroll
        for (int c = 0; c < HEADC; c++) acc[c] += a * wh[c * 512 + ci];
    }
    #pragma unroll
    for (int c = 0; c < HEADC; c++) {
        float v = acc[c];
        v += __shfl_down(v, 32); v += __shfl_down(v, 16); v += __shfl_down(v, 8);
        v += __shfl_down(v, 4);  v += __shfl_down(v, 2);  v += __shfl_down(v, 1);
        if (lane == 0) pred[(size_t)cellid * HEADC + c] = v;
    }
}

// ---- decode ----
__global__ void decode_kernel(const float* __restrict__ pred, float* __restrict__ out,
                              float* __restrict__ cls) {
    int i = blockIdx.x * 256 + threadIdx.x;
    if (i >= BATCH * NCELLS) return;
    const float* p = pred + (size_t)i * HEADC;
    int cell = i % NCELLS;
    int gx = cell % 14, gy = cell / 14;
    float conf = 1.f / (1.f + expf(-p[0]));
    float m = p[1];
    #pragma unroll
    for (int c = 1; c < NCLS; c++) m = fmaxf(m, p[1 + c]);
    float e[NCLS], s = 0.f;
    #pragma unroll
    for (int c = 0; c < NCLS; c++) { e[c] = expf(p[1 + c] - m); s += e[c]; }
    float inv = conf / s;
    #pragma unroll
    for (int c = 0; c < NCLS; c++) cls[(size_t)i * NCLS + c] = e[c] * inv;
    float cx = (1.f / (1.f + expf(-p[21])) + gx) * 32.f;
    float cy = (1.f / (1.f + expf(-p[22])) + gy) * 32.f;
    float w  = expf(p[23]) * 32.f;
    float h  = expf(p[24]) * 32.f;
    float x1 = (cx - 0.5f * w) / 448.f, y1 = (cy - 0.5f * h) / 448.f;
    float x2 = (cx + 0.5f * w) / 448.f, y2 = (cy + 0.5f * h) / 448.f;
    x1 = fminf(fmaxf(x1, 0.f), 1.f); y1 = fminf(fmaxf(y1, 0.f), 1.f);
    x2 = fminf(fmaxf(x2, 0.f), 1.f); y2 = fminf(fmaxf(y2, 0.f), 1.f);
    float* o = out + (size_t)i * 24;
    o[0] = x1; o[1] = y1; o[2] = x2; o[3] = y2;
}

// ---- IoU ----
__global__ void iou_kernel(const float* __restrict__ out, float* __restrict__ iou) {
    int idx = blockIdx.x * 256 + threadIdx.x;
    if (idx >= BATCH * NCELLS * NCELLS) return;
    int j = idx % NCELLS;
    int i = (idx / NCELLS) % NCELLS;
    int b = idx / (NCELLS * NCELLS);
    const float* bi = out + (((size_t)b * NCELLS) + i) * 24;
    const float* bj = out + (((size_t)b * NCELLS) + j) * 24;
    float ai = fmaxf(bi[2] - bi[0], 0.f) * fmaxf(bi[3] - bi[1], 0.f);
    float aj = fmaxf(bj[2] - bj[0], 0.f) * fmaxf(bj[3] - bj[1], 0.f);
    float ix1 = fmaxf(bi[0], bj[0]), iy1 = fmaxf(bi[1], bj[1]);
    float ix2 = fminf(bi[2], bj[2]), iy2 = fminf(bi[3], bj[3]);
    float inter = fmaxf(ix2 - ix1, 0.f) * fmaxf(iy2 - iy1, 0.f);
    iou[idx] = inter / (ai + aj - inter + 1e-14f);
}

// ---- NMS ----
__global__ void nms_kernel(const float* __restrict__ cls, const float* __restrict__ iou,
                           float* __restrict__ out) {
    int b = blockIdx.x / NCLS;
    int c = blockIdx.x % NCLS;
    __shared__ float sc[NCELLS];
    __shared__ float ssort[NCELLS];
    __shared__ int   ord[NCELLS];
    __shared__ int   kp[NCELLS];
    int j = threadIdx.x;
    float sj = 0.f;
    if (j < NCELLS) {
        sj = cls[(((size_t)b * NCELLS) + j) * NCLS + c];
        sc[j] = sj;
    }
    __syncthreads();
    if (j < NCELLS) {
        int r = 0;
        for (int k = 0; k < NCELLS; k++) {
            float sk = sc[k];
            r += (sk > sj) || (sk == sj && k < j);
        }
        ord[r] = j; ssort[r] = sj; kp[r] = (sj > 0.01f) ? 1 : 0;
    }
    __syncthreads();
    int myo = (j < NCELLS) ? ord[j] : 0;
    const float* iob = iou + (size_t)b * NCELLS * NCELLS;
    for (int i = 0; i < NCELLS; i++) {
        __syncthreads();
        if (!kp[i]) continue;
        if (j > i && j < NCELLS && kp[j]) {
            if (iob[ord[i] * NCELLS + myo] > 0.5f) kp[j] = 0;
        }
    }
    __syncthreads();
    if (j < NCELLS)
        out[(((size_t)b * NCELLS) + ord[j]) * 24 + 4 + c] = kp[j] ? ssort[j] : 0.f;
}

// ---- launch ----
extern "C" void kernel_launch(void* const* d_in, const int* in_sizes, int n_in,
                              void* d_out, int out_size, void* d_ws, size_t ws_size,
                              hipStream_t stream) {
    const float* x  = (const float*)d_in[0];
    const float* w1 = (const float*)d_in[1];
    const float* w2 = (const float*)d_in[2];
    const float* w3 = (const float*)d_in[3];
    const float* w4 = (const float*)d_in[4];
    const float* w5 = (const float*)d_in[5];
    const float* wh = (const float*)d_in[6];
    float* out = (float*)d_out;
    char* base = (char*)d_ws;

    // region A (0 .. 102,760,448)
    unsigned short* a1h = (unsigned short*)(base);
    unsigned short* a1l = a1h + 25690112;
    unsigned short* a3h = (unsigned short*)(base);
    unsigned short* a3l = a3h + 6422528;
    float*          part5 = (float*)(base);
    unsigned short* a5h = (unsigned short*)(base + 12845056);
    unsigned short* a5l = a5h + 802816;
    float* pred = (float*)(base + 16056320);
    float* clsb = (float*)(base + 16213120);
    float* ioub = (float*)(base + 16338560);
    // region B (102,760,448 .. 154,140,672)
    unsigned short* a2h = (unsigned short*)(base + 102760448);
    unsigned short* a2l = a2h + 12845056;
    unsigned short* a4h = (unsigned short*)(base + 102760448);
    unsigned short* a4l = a4h + 3211264;
    // weights
    unsigned short* w2h = (unsigned short*)(base + 154140672);
    unsigned short* w3h = w2h + 73728;
    unsigned short* w4h = w3h + 294912;
    unsigned short* w5h = w4h + 1179648;
    unsigned short* w2l = (unsigned short*)(base + 161955840);
    unsigned short* w3l = w2l + 73728;
    unsigned short* w4l = w3l + 294912;
    unsigned short* w5l = w4l + 1179648;

    prep_w<64, 128> <<<288,  256, 0, stream>>>(w2, w2h, w2l);
    prep_w<128, 256><<<1152, 256, 0, stream>>>(w3, w3h, w3l);
    prep_w<256, 512><<<4608, 256, 0, stream>>>(w4, w4h, w4l);
    prep_w<512, 512><<<9216, 256, 0, stream>>>(w5, w5h, w5l);

    conv1_kernel<<<12544, 256, 0, stream>>>(x, w1, a1h, a1l);

    conv_mfma<64, 128, 224, 224, 1, false><<<1568, 256, 0, stream>>>(
        a1h, a1l, w2h, w2l, a2h, a2l, nullptr);
    conv_mfma<128, 256, 112, 112, 1, false><<<784, 256, 0, stream>>>(
        a2h, a2l, w3h, w3l, a3h, a3l, nullptr);
    conv_mfma<256, 512, 56, 56, 1, false><<<512, 256, 0, stream>>>(
        a3h, a3l, w4h, w4l, a4h, a4l, nullptr);
    conv_mfma<512, 512, 28, 28, 4, true><<<512, 256, 0, stream>>>(
        a4h, a4l, w5h, w5l, nullptr, nullptr, part5);
    reduce4_split<<<784, 256, 0, stream>>>(part5, a5h, a5l);

    head_kernel<<<392, 256, 0, stream>>>(a5h, a5l, wh, pred);
    decode_kernel<<<7, 256, 0, stream>>>(pred, out, clsb);
    iou_kernel<<<1201, 256, 0, stream>>>(out, ioub);
    nms_kernel<<<160, 256, 0, stream>>>(clsb, ioub, out);
}

// Round 7
// 468.713 us; speedup vs baseline: 18.5063x; 1.1012x over previous
//
#include <hip/hip_runtime.h>
#include <math.h>

#define BATCH 8
#define NCELLS 196
#define NCLS 20
#define HEADC 25

typedef __attribute__((ext_vector_type(8))) short short8;
typedef __attribute__((ext_vector_type(4))) float f32x4;
#define MFMA16(a,b,c) __builtin_amdgcn_mfma_f32_16x16x32_bf16(a,b,c,0,0,0)

// ---- bf16 split helpers (RNE via bit ops; deterministic) ----
__device__ __forceinline__ unsigned short f2bf(float x) {
    union { float f; unsigned u; } a; a.f = x;
    unsigned r = a.u + 0x7FFFu + ((a.u >> 16) & 1u);
    return (unsigned short)(r >> 16);
}
__device__ __forceinline__ float bf2f(unsigned short h) {
    union { unsigned u; float f; } a; a.u = ((unsigned)h) << 16;
    return a.f;
}
__device__ __forceinline__ void split_bf(float x, unsigned short& h, unsigned short& l) {
    h = f2bf(x);
    l = f2bf(x - bf2f(h));
}

// ---- weight prep: w[co][ci][3][3] fp32 -> MFMA-A-fragment-ordered hi/lo bf16 ----
template<int CIN, int COUT>
__global__ void prep_w(const float* __restrict__ w, unsigned short* __restrict__ whi,
                       unsigned short* __restrict__ wlo) {
    constexpr int G = COUT / 16, CH = CIN / 32;
    int idx = blockIdx.x * 256 + threadIdx.x;
    if (idx >= 9 * CIN * COUT) return;
    int j    = idx & 7;
    int lane = (idx >> 3) & 63;
    int fg   = idx >> 9;
    int g    = fg % G;
    int fc   = fg / G;
    int chunk = fc % CH;
    int plane = fc / CH;
    int m = lane & 15, quad = lane >> 4;
    int co = g * 16 + m;
    int ci = chunk * 32 + quad * 8 + j;
    int ky = plane / 3, kx = plane % 3;
    float v = w[((co * CIN + ci) * 3 + ky) * 3 + kx];
    unsigned short h, l; split_bf(v, h, l);
    whi[idx] = h; wlo[idx] = l;
}

// ---- conv1: 3->64, 448->224, fp32 compute, coalesced NHWC hi/lo stores ----
__global__ void conv1_kernel(const float* __restrict__ x, const float* __restrict__ w1,
                             unsigned short* __restrict__ ohi, unsigned short* __restrict__ olo) {
    __shared__ float sW[27][64];
    __shared__ float sX[3][3][66];
    int bid = blockIdx.x;
    int xseg = bid % 7;  bid /= 7;
    int oy   = bid % 224;
    int b    = bid / 224;
    int ox0  = xseg * 32;

    for (int e = threadIdx.x; e < 1728; e += 256) {
        int k = e >> 6, co = e & 63;
        sW[k][co] = w1[co * 27 + k];
    }
    for (int e = threadIdx.x; e < 594; e += 256) {
        int ci = e / 198;
        int r  = e - ci * 198;
        int ky = r / 66;
        int lx = r - ky * 66;
        int iy = 2 * oy + ky;
        int ix = 2 * ox0 + lx;
        float v = 0.f;
        if (lx < 65 && iy < 448 && ix < 448)
            v = x[(((size_t)b * 3 + ci) * 448 + iy) * 448 + ix];
        sX[ci][ky][lx] = v;
    }
    __syncthreads();

    int pxl = threadIdx.x >> 3;
    int cog = threadIdx.x & 7;
    float acc[8] = {0.f,0.f,0.f,0.f,0.f,0.f,0.f,0.f};
    #pragma unroll
    for (int ci = 0; ci < 3; ci++) {
        #pragma unroll
        for (int ky = 0; ky < 3; ky++) {
            const float* row = sX[ci][ky];
            #pragma unroll
            for (int kx = 0; kx < 3; kx++) {
                float iv = row[2 * pxl + kx];
                int k = (ci * 3 + ky) * 3 + kx;
                float4 wa = *(const float4*)&sW[k][cog * 8];
                float4 wb = *(const float4*)&sW[k][cog * 8 + 4];
                acc[0] += wa.x * iv; acc[1] += wa.y * iv; acc[2] += wa.z * iv; acc[3] += wa.w * iv;
                acc[4] += wb.x * iv; acc[5] += wb.y * iv; acc[6] += wb.z * iv; acc[7] += wb.w * iv;
            }
        }
    }
    union { unsigned short u[8]; uint4 v; } ph, pl;
    #pragma unroll
    for (int u = 0; u < 8; u++) {
        float v = fmaxf(acc[u], 0.f);
        split_bf(v, ph.u[u], pl.u[u]);
    }
    size_t base = ((size_t)(b * 224 + oy) * 224 + ox0 + pxl) * 64 + cog * 8;
    *(uint4*)&ohi[base] = ph.v;
    *(uint4*)&olo[base] = pl.v;
}

// ---- MFMA conv: 3x3 stride2 SAME, NHWC hi/lo in, NHWC hi/lo out (or fp32 partial) ----
// R7: px slot = 32 ushorts (64B, truly 16B-aligned) + XOR-quad swizzle
//   16B-unit index u = px*4 + (quad ^ ((px>>1)&3))
// LDS = 36,992B -> 4 blocks/CU (was 41,984B -> 2-3); launch_bounds(256,4).
template<int CIN, int COUT, int HIN, int WIN, int KSPLIT, bool PARTIAL>
__launch_bounds__(256, 4)
__global__ void conv_mfma(const unsigned short* __restrict__ ahi, const unsigned short* __restrict__ alo,
                          const unsigned short* __restrict__ whi, const unsigned short* __restrict__ wlo,
                          unsigned short* __restrict__ ohi, unsigned short* __restrict__ olo,
                          float* __restrict__ part) {
    constexpr int HOUT = HIN / 2, WOUT = WIN / 2;
    constexpr int TX = (WOUT + 7) / 8, TY = (HOUT + 7) / 8;
    constexpr int COG = COUT / 128;
    constexpr int CH_TOT = CIN / 32;
    constexpr int CH = CH_TOT / KSPLIT;
    constexpr int G = COUT / 16;
    constexpr int PLANE_E = 17 * 17 * 32;        // 9248 ushorts per hi/lo plane
    constexpr size_t PSZ = (size_t)BATCH * HOUT * WOUT * COUT;

    __shared__ __align__(16) unsigned short sA[2 * PLANE_E];   // 36,992 B

    int bid = blockIdx.x;
    int ks  = bid % KSPLIT; bid /= KSPLIT;
    int txi = bid % TX;     bid /= TX;
    int tyi = bid % TY;     bid /= TY;
    int cg  = bid % COG;
    int b   = bid / COG;
    int oy0 = tyi * 8, ox0 = txi * 8;
    int iy0 = oy0 * 2, ix0 = ox0 * 2;

    int tid = threadIdx.x;
    int w   = tid >> 6;
    int lane = tid & 63;
    int n = lane & 15, quad = lane >> 4;

    int oyl[4], oxl[4], pbase[4];
    #pragma unroll
    for (int nt = 0; nt < 4; nt++) {
        int oyq = nt >> 1, oxq = nt & 1;
        int oy_off = oyq * 4 + (n >> 2);
        int ox_off = oxq * 4 + (n & 3);
        oyl[nt] = oy0 + oy_off;
        oxl[nt] = ox0 + ox_off;
        pbase[nt] = 2 * oy_off * 17 + 2 * ox_off;
    }

    f32x4 zero = {0.f, 0.f, 0.f, 0.f};
    f32x4 acc[2][4];
    #pragma unroll
    for (int ct = 0; ct < 2; ct++)
        #pragma unroll
        for (int nt = 0; nt < 4; nt++) acc[ct][nt] = zero;

    int g0 = cg * 8 + w * 2;

    for (int ch = 0; ch < CH; ch++) {
        int chunk = ks * CH + ch;
        int ci0 = chunk * 32;
        __syncthreads();
        // ---- stage act tile: 17x17 px x 32 ci, hi+lo, swizzled 16B units ----
        for (int e = tid; e < 17 * 17 * 8; e += 256) {
            int pxi = e >> 3, grp = e & 7;
            int liy = pxi / 17, lix = pxi - liy * 17;
            int iy = iy0 + liy, ix = ix0 + lix;
            uint4 v = make_uint4(0u, 0u, 0u, 0u);
            if (iy < HIN && ix < WIN) {
                const unsigned short* src = ((grp & 4) ? alo : ahi)
                    + ((size_t)(b * HIN + iy) * WIN + ix) * CIN + ci0 + (grp & 3) * 8;
                v = *(const uint4*)src;
            }
            int u = pxi * 4 + ((grp & 3) ^ ((pxi >> 1) & 3));
            *(uint4*)&sA[((grp >> 2) ? PLANE_E : 0) + u * 8] = v;
        }
        __syncthreads();
        #pragma unroll
        for (int pl = 0; pl < 9; pl++) {
            int ky = pl / 3, kx = pl % 3;
            size_t fbase = ((size_t)(pl * CH_TOT + chunk) * G + g0) * 512 + lane * 8;
            short8 Ah0 = *(const short8*)(whi + fbase);
            short8 Ah1 = *(const short8*)(whi + fbase + 512);
            short8 Al0 = *(const short8*)(wlo + fbase);
            short8 Al1 = *(const short8*)(wlo + fbase + 512);
            int dp = ky * 17 + kx;
            #pragma unroll
            for (int nt = 0; nt < 4; nt++) {
                int p = pbase[nt] + dp;
                int u = p * 4 + (quad ^ ((p >> 1) & 3));
                short8 Bh = *(const short8*)&sA[u * 8];
                short8 Bl = *(const short8*)&sA[PLANE_E + u * 8];
                acc[0][nt] = MFMA16(Ah0, Bh, acc[0][nt]);
                acc[0][nt] = MFMA16(Ah0, Bl, acc[0][nt]);
                acc[0][nt] = MFMA16(Al0, Bh, acc[0][nt]);
                acc[1][nt] = MFMA16(Ah1, Bh, acc[1][nt]);
                acc[1][nt] = MFMA16(Ah1, Bl, acc[1][nt]);
                acc[1][nt] = MFMA16(Al1, Bh, acc[1][nt]);
            }
        }
    }
    int cob = cg * 128 + w * 32;
    #pragma unroll
    for (int ct = 0; ct < 2; ct++) {
        #pragma unroll
        for (int nt = 0; nt < 4; nt++) {
            if (oyl[nt] >= HOUT || oxl[nt] >= WOUT) continue;
            size_t base = ((size_t)(b * HOUT + oyl[nt]) * WOUT + oxl[nt]) * COUT
                          + cob + ct * 16 + quad * 4;
            if (PARTIAL) {
                *(f32x4*)&part[(size_t)ks * PSZ + base] = acc[ct][nt];
            } else {
                unsigned long long h64 = 0ull, l64 = 0ull;
                #pragma unroll
                for (int r = 0; r < 4; r++) {
                    float v = fmaxf(acc[ct][nt][r], 0.f);
                    unsigned short hh, ll; split_bf(v, hh, ll);
                    h64 |= ((unsigned long long)hh) << (16 * r);
                    l64 |= ((unsigned long long)ll) << (16 * r);
                }
                *(unsigned long long*)&ohi[base] = h64;
                *(unsigned long long*)&olo[base] = l64;
            }
        }
    }
}

// ---- reduce KS K-split fp32 partials -> ReLU -> hi/lo bf16 ----
template<int KS>
__global__ void reduceN_split(const float* __restrict__ p, unsigned short* __restrict__ oh,
                              unsigned short* __restrict__ ol, int n) {
    int n4 = n >> 2;
    int i = blockIdx.x * 256 + threadIdx.x;
    if (i >= n4) return;
    const float4* p4 = (const float4*)p;
    float4 s = p4[i];
    #pragma unroll
    for (int k = 1; k < KS; k++) {
        float4 t = p4[i + (size_t)k * n4];
        s.x += t.x; s.y += t.y; s.z += t.z; s.w += t.w;
    }
    float v[4] = { fmaxf(s.x,0.f), fmaxf(s.y,0.f), fmaxf(s.z,0.f), fmaxf(s.w,0.f) };
    unsigned long long h64 = 0ull, l64 = 0ull;
    #pragma unroll
    for (int r = 0; r < 4; r++) {
        unsigned short hh, ll; split_bf(v[r], hh, ll);
        h64 |= ((unsigned long long)hh) << (16 * r);
        l64 |= ((unsigned long long)ll) << (16 * r);
    }
    *(unsigned long long*)&oh[i * 4] = h64;
    *(unsigned long long*)&ol[i * 4] = l64;
}

// ---- 1x1 head ----
__global__ void head_kernel(const unsigned short* __restrict__ ah, const unsigned short* __restrict__ al,
                            const float* __restrict__ wh, float* __restrict__ pred) {
    int wave = threadIdx.x >> 6;
    int lane = threadIdx.x & 63;
    int cellid = blockIdx.x * 4 + wave;
    float acc[HEADC];
    #pragma unroll
    for (int c = 0; c < HEADC; c++) acc[c] = 0.f;
    for (int it = 0; it < 8; it++) {
        int ci = it * 64 + lane;
        size_t idx = (size_t)cellid * 512 + ci;
        float a = bf2f(ah[idx]) + bf2f(al[idx]);
        #pragma unroll
        for (int c = 0; c < HEADC; c++) acc[c] += a * wh[c * 512 + ci];
    }
    #pragma unroll
    for (int c = 0; c < HEADC; c++) {
        float v = acc[c];
        v += __shfl_down(v, 32); v += __shfl_down(v, 16); v += __shfl_down(v, 8);
        v += __shfl_down(v, 4);  v += __shfl_down(v, 2);  v += __shfl_down(v, 1);
        if (lane == 0) pred[(size_t)cellid * HEADC + c] = v;
    }
}

// ---- decode ----
__global__ void decode_kernel(const float* __restrict__ pred, float* __restrict__ out,
                              float* __restrict__ cls) {
    int i = blockIdx.x * 256 + threadIdx.x;
    if (i >= BATCH * NCELLS) return;
    const float* p = pred + (size_t)i * HEADC;
    int cell = i % NCELLS;
    int gx = cell % 14, gy = cell / 14;
    float conf = 1.f / (1.f + expf(-p[0]));
    float m = p[1];
    #pragma unroll
    for (int c = 1; c < NCLS; c++) m = fmaxf(m, p[1 + c]);
    float e[NCLS], s = 0.f;
    #pragma unroll
    for (int c = 0; c < NCLS; c++) { e[c] = expf(p[1 + c] - m); s += e[c]; }
    float inv = conf / s;
    #pragma unroll
    for (int c = 0; c < NCLS; c++) cls[(size_t)i * NCLS + c] = e[c] * inv;
    float cx = (1.f / (1.f + expf(-p[21])) + gx) * 32.f;
    float cy = (1.f / (1.f + expf(-p[22])) + gy) * 32.f;
    float w  = expf(p[23]) * 32.f;
    float h  = expf(p[24]) * 32.f;
    float x1 = (cx - 0.5f * w) / 448.f, y1 = (cy - 0.5f * h) / 448.f;
    float x2 = (cx + 0.5f * w) / 448.f, y2 = (cy + 0.5f * h) / 448.f;
    x1 = fminf(fmaxf(x1, 0.f), 1.f); y1 = fminf(fmaxf(y1, 0.f), 1.f);
    x2 = fminf(fmaxf(x2, 0.f), 1.f); y2 = fminf(fmaxf(y2, 0.f), 1.f);
    float* o = out + (size_t)i * 24;
    o[0] = x1; o[1] = y1; o[2] = x2; o[3] = y2;
}

// ---- IoU ----
__global__ void iou_kernel(const float* __restrict__ out, float* __restrict__ iou) {
    int idx = blockIdx.x * 256 + threadIdx.x;
    if (idx >= BATCH * NCELLS * NCELLS) return;
    int j = idx % NCELLS;
    int i = (idx / NCELLS) % NCELLS;
    int b = idx / (NCELLS * NCELLS);
    const float* bi = out + (((size_t)b * NCELLS) + i) * 24;
    const float* bj = out + (((size_t)b * NCELLS) + j) * 24;
    float ai = fmaxf(bi[2] - bi[0], 0.f) * fmaxf(bi[3] - bi[1], 0.f);
    float aj = fmaxf(bj[2] - bj[0], 0.f) * fmaxf(bj[3] - bj[1], 0.f);
    float ix1 = fmaxf(bi[0], bj[0]), iy1 = fmaxf(bi[1], bj[1]);
    float ix2 = fminf(bi[2], bj[2]), iy2 = fminf(bi[3], bj[3]);
    float inter = fmaxf(ix2 - ix1, 0.f) * fmaxf(iy2 - iy1, 0.f);
    iou[idx] = inter / (ai + aj - inter + 1e-14f);
}

// ---- NMS ----
__global__ void nms_kernel(const float* __restrict__ cls, const float* __restrict__ iou,
                           float* __restrict__ out) {
    int b = blockIdx.x / NCLS;
    int c = blockIdx.x % NCLS;
    __shared__ float sc[NCELLS];
    __shared__ float ssort[NCELLS];
    __shared__ int   ord[NCELLS];
    __shared__ int   kp[NCELLS];
    int j = threadIdx.x;
    float sj = 0.f;
    if (j < NCELLS) {
        sj = cls[(((size_t)b * NCELLS) + j) * NCLS + c];
        sc[j] = sj;
    }
    __syncthreads();
    if (j < NCELLS) {
        int r = 0;
        for (int k = 0; k < NCELLS; k++) {
            float sk = sc[k];
            r += (sk > sj) || (sk == sj && k < j);
        }
        ord[r] = j; ssort[r] = sj; kp[r] = (sj > 0.01f) ? 1 : 0;
    }
    __syncthreads();
    int myo = (j < NCELLS) ? ord[j] : 0;
    const float* iob = iou + (size_t)b * NCELLS * NCELLS;
    for (int i = 0; i < NCELLS; i++) {
        __syncthreads();
        if (!kp[i]) continue;
        if (j > i && j < NCELLS && kp[j]) {
            if (iob[ord[i] * NCELLS + myo] > 0.5f) kp[j] = 0;
        }
    }
    __syncthreads();
    if (j < NCELLS)
        out[(((size_t)b * NCELLS) + ord[j]) * 24 + 4 + c] = kp[j] ? ssort[j] : 0.f;
}

// ---- launch ----
extern "C" void kernel_launch(void* const* d_in, const int* in_sizes, int n_in,
                              void* d_out, int out_size, void* d_ws, size_t ws_size,
                              hipStream_t stream) {
    const float* x  = (const float*)d_in[0];
    const float* w1 = (const float*)d_in[1];
    const float* w2 = (const float*)d_in[2];
    const float* w3 = (const float*)d_in[3];
    const float* w4 = (const float*)d_in[4];
    const float* w5 = (const float*)d_in[5];
    const float* wh = (const float*)d_in[6];
    float* out = (float*)d_out;
    char* base = (char*)d_ws;

    // region A (0 .. 102,760,448)
    unsigned short* a1h = (unsigned short*)(base);
    unsigned short* a1l = a1h + 25690112;
    unsigned short* a3h = (unsigned short*)(base);          // overlays a1 (dead after conv2)
    unsigned short* a3l = a3h + 6422528;
    float* part4 = (float*)(base + 25690112);               // 2 x 3,211,264 fp32 = 25.7 MB
    float* part5 = (float*)(base);                          // 8 x 802,816 fp32 = 25.7 MB (a3 dead)
    unsigned short* a5h = (unsigned short*)(base + 51380224);
    unsigned short* a5l = a5h + 802816;
    float* pred = (float*)(base + 54589440);
    float* clsb = (float*)(base + 54746240);
    float* ioub = (float*)(base + 54871680);
    // region B (102,760,448 .. 154,140,672)
    unsigned short* a2h = (unsigned short*)(base + 102760448);
    unsigned short* a2l = a2h + 12845056;
    unsigned short* a4h = (unsigned short*)(base + 102760448);  // overlays a2 (dead after conv3)
    unsigned short* a4l = a4h + 3211264;
    // weights
    unsigned short* w2h = (unsigned short*)(base + 154140672);
    unsigned short* w3h = w2h + 73728;
    unsigned short* w4h = w3h + 294912;
    unsigned short* w5h = w4h + 1179648;
    unsigned short* w2l = (unsigned short*)(base + 161955840);
    unsigned short* w3l = w2l + 73728;
    unsigned short* w4l = w3l + 294912;
    unsigned short* w5l = w4l + 1179648;

    prep_w<64, 128> <<<288,  256, 0, stream>>>(w2, w2h, w2l);
    prep_w<128, 256><<<1152, 256, 0, stream>>>(w3, w3h, w3l);
    prep_w<256, 512><<<4608, 256, 0, stream>>>(w4, w4h, w4l);
    prep_w<512, 512><<<9216, 256, 0, stream>>>(w5, w5h, w5l);

    conv1_kernel<<<12544, 256, 0, stream>>>(x, w1, a1h, a1l);

    // conv2: 64->128, 224->112 : 8b * 14*14 * COG1 = 1568 blocks
    conv_mfma<64, 128, 224, 224, 1, false><<<1568, 256, 0, stream>>>(
        a1h, a1l, w2h, w2l, a2h, a2l, nullptr);
    // conv3: 128->256, 112->56 : 8 * 7*7 * 2 = 784
    conv_mfma<128, 256, 112, 112, 1, false><<<784, 256, 0, stream>>>(
        a2h, a2l, w3h, w3l, a3h, a3l, nullptr);
    // conv4: 256->512, 56->28 : 8 * 4*4 * 4 * KS2 = 1024
    conv_mfma<256, 512, 56, 56, 2, true><<<1024, 256, 0, stream>>>(
        a3h, a3l, w4h, w4l, nullptr, nullptr, part4);
    reduceN_split<2><<<3136, 256, 0, stream>>>(part4, a4h, a4l, 3211264);
    // conv5: 512->512, 28->14 : 8 * 2*2 * 4 * KS8 = 1024
    conv_mfma<512, 512, 28, 28, 8, true><<<1024, 256, 0, stream>>>(
        a4h, a4l, w5h, w5l, nullptr, nullptr, part5);
    reduceN_split<8><<<784, 256, 0, stream>>>(part5, a5h, a5l, 802816);

    head_kernel<<<392, 256, 0, stream>>>(a5h, a5l, wh, pred);
    decode_kernel<<<7, 256, 0, stream>>>(pred, out, clsb);
    iou_kernel<<<1201, 256, 0, stream>>>(out, ioub);
    nms_kernel<<<160, 256, 0, stream>>>(clsb, ioub, out);
}

// Round 8
// 445.586 us; speedup vs baseline: 19.4668x; 1.0519x over previous
//
#include <hip/hip_runtime.h>
#include <math.h>

#define BATCH 8
#define NCELLS 196
#define NCLS 20
#define HEADC 25

typedef __attribute__((ext_vector_type(8))) short short8;
typedef __attribute__((ext_vector_type(4))) float f32x4;
#define MFMA16(a,b,c) __builtin_amdgcn_mfma_f32_16x16x32_bf16(a,b,c,0,0,0)

// ---- bf16 split helpers (RNE via bit ops; deterministic) ----
__device__ __forceinline__ unsigned short f2bf(float x) {
    union { float f; unsigned u; } a; a.f = x;
    unsigned r = a.u + 0x7FFFu + ((a.u >> 16) & 1u);
    return (unsigned short)(r >> 16);
}
__device__ __forceinline__ float bf2f(unsigned short h) {
    union { unsigned u; float f; } a; a.u = ((unsigned)h) << 16;
    return a.f;
}
__device__ __forceinline__ void split_bf(float x, unsigned short& h, unsigned short& l) {
    h = f2bf(x);
    l = f2bf(x - bf2f(h));
}

// ---- weight prep: w[co][ci][3][3] fp32 -> MFMA-A-fragment-ordered hi/lo bf16 ----
template<int CIN, int COUT>
__global__ void prep_w(const float* __restrict__ w, unsigned short* __restrict__ whi,
                       unsigned short* __restrict__ wlo) {
    constexpr int G = COUT / 16, CH = CIN / 32;
    int idx = blockIdx.x * 256 + threadIdx.x;
    if (idx >= 9 * CIN * COUT) return;
    int j    = idx & 7;
    int lane = (idx >> 3) & 63;
    int fg   = idx >> 9;
    int g    = fg % G;
    int fc   = fg / G;
    int chunk = fc % CH;
    int plane = fc / CH;
    int m = lane & 15, quad = lane >> 4;
    int co = g * 16 + m;
    int ci = chunk * 32 + quad * 8 + j;
    int ky = plane / 3, kx = plane % 3;
    float v = w[((co * CIN + ci) * 3 + ky) * 3 + kx];
    unsigned short h, l; split_bf(v, h, l);
    whi[idx] = h; wlo[idx] = l;
}

// ---- conv1: 3->64, 448->224, fp32 compute, coalesced NHWC hi/lo stores ----
__global__ void conv1_kernel(const float* __restrict__ x, const float* __restrict__ w1,
                             unsigned short* __restrict__ ohi, unsigned short* __restrict__ olo) {
    __shared__ float sW[27][64];
    __shared__ float sX[3][3][66];
    int bid = blockIdx.x;
    int xseg = bid % 7;  bid /= 7;
    int oy   = bid % 224;
    int b    = bid / 224;
    int ox0  = xseg * 32;

    for (int e = threadIdx.x; e < 1728; e += 256) {
        int k = e >> 6, co = e & 63;
        sW[k][co] = w1[co * 27 + k];
    }
    for (int e = threadIdx.x; e < 594; e += 256) {
        int ci = e / 198;
        int r  = e - ci * 198;
        int ky = r / 66;
        int lx = r - ky * 66;
        int iy = 2 * oy + ky;
        int ix = 2 * ox0 + lx;
        float v = 0.f;
        if (lx < 65 && iy < 448 && ix < 448)
            v = x[(((size_t)b * 3 + ci) * 448 + iy) * 448 + ix];
        sX[ci][ky][lx] = v;
    }
    __syncthreads();

    int pxl = threadIdx.x >> 3;
    int cog = threadIdx.x & 7;
    float acc[8] = {0.f,0.f,0.f,0.f,0.f,0.f,0.f,0.f};
    #pragma unroll
    for (int ci = 0; ci < 3; ci++) {
        #pragma unroll
        for (int ky = 0; ky < 3; ky++) {
            const float* row = sX[ci][ky];
            #pragma unroll
            for (int kx = 0; kx < 3; kx++) {
                float iv = row[2 * pxl + kx];
                int k = (ci * 3 + ky) * 3 + kx;
                float4 wa = *(const float4*)&sW[k][cog * 8];
                float4 wb = *(const float4*)&sW[k][cog * 8 + 4];
                acc[0] += wa.x * iv; acc[1] += wa.y * iv; acc[2] += wa.z * iv; acc[3] += wa.w * iv;
                acc[4] += wb.x * iv; acc[5] += wb.y * iv; acc[6] += wb.z * iv; acc[7] += wb.w * iv;
            }
        }
    }
    union { unsigned short u[8]; uint4 v; } ph, pl;
    #pragma unroll
    for (int u = 0; u < 8; u++) {
        float v = fmaxf(acc[u], 0.f);
        split_bf(v, ph.u[u], pl.u[u]);
    }
    size_t base = ((size_t)(b * 224 + oy) * 224 + ox0 + pxl) * 64 + cog * 8;
    *(uint4*)&ohi[base] = ph.v;
    *(uint4*)&olo[base] = pl.v;
}

// ---- MFMA conv: 3x3 stride2 SAME, NHWC hi/lo in, NHWC hi/lo out (or fp32 partial) ----
template<int CIN, int COUT, int HIN, int WIN, int KSPLIT, bool PARTIAL>
__launch_bounds__(256, 4)
__global__ void conv_mfma(const unsigned short* __restrict__ ahi, const unsigned short* __restrict__ alo,
                          const unsigned short* __restrict__ whi, const unsigned short* __restrict__ wlo,
                          unsigned short* __restrict__ ohi, unsigned short* __restrict__ olo,
                          float* __restrict__ part) {
    constexpr int HOUT = HIN / 2, WOUT = WIN / 2;
    constexpr int TX = (WOUT + 7) / 8, TY = (HOUT + 7) / 8;
    constexpr int COG = COUT / 128;
    constexpr int CH_TOT = CIN / 32;
    constexpr int CH = CH_TOT / KSPLIT;
    constexpr int G = COUT / 16;
    constexpr int PLANE_E = 17 * 17 * 32;
    constexpr size_t PSZ = (size_t)BATCH * HOUT * WOUT * COUT;

    __shared__ __align__(16) unsigned short sA[2 * PLANE_E];

    int bid = blockIdx.x;
    int ks  = bid % KSPLIT; bid /= KSPLIT;
    int txi = bid % TX;     bid /= TX;
    int tyi = bid % TY;     bid /= TY;
    int cg  = bid % COG;
    int b   = bid / COG;
    int oy0 = tyi * 8, ox0 = txi * 8;
    int iy0 = oy0 * 2, ix0 = ox0 * 2;

    int tid = threadIdx.x;
    int w   = tid >> 6;
    int lane = tid & 63;
    int n = lane & 15, quad = lane >> 4;

    int oyl[4], oxl[4], pbase[4];
    #pragma unroll
    for (int nt = 0; nt < 4; nt++) {
        int oyq = nt >> 1, oxq = nt & 1;
        int oy_off = oyq * 4 + (n >> 2);
        int ox_off = oxq * 4 + (n & 3);
        oyl[nt] = oy0 + oy_off;
        oxl[nt] = ox0 + ox_off;
        pbase[nt] = 2 * oy_off * 17 + 2 * ox_off;
    }

    f32x4 zero = {0.f, 0.f, 0.f, 0.f};
    f32x4 acc[2][4];
    #pragma unroll
    for (int ct = 0; ct < 2; ct++)
        #pragma unroll
        for (int nt = 0; nt < 4; nt++) acc[ct][nt] = zero;

    int g0 = cg * 8 + w * 2;

    for (int ch = 0; ch < CH; ch++) {
        int chunk = ks * CH + ch;
        int ci0 = chunk * 32;
        __syncthreads();
        for (int e = tid; e < 17 * 17 * 8; e += 256) {
            int pxi = e >> 3, grp = e & 7;
            int liy = pxi / 17, lix = pxi - liy * 17;
            int iy = iy0 + liy, ix = ix0 + lix;
            uint4 v = make_uint4(0u, 0u, 0u, 0u);
            if (iy < HIN && ix < WIN) {
                const unsigned short* src = ((grp & 4) ? alo : ahi)
                    + ((size_t)(b * HIN + iy) * WIN + ix) * CIN + ci0 + (grp & 3) * 8;
                v = *(const uint4*)src;
            }
            int u = pxi * 4 + ((grp & 3) ^ ((pxi >> 1) & 3));
            *(uint4*)&sA[((grp >> 2) ? PLANE_E : 0) + u * 8] = v;
        }
        __syncthreads();
        #pragma unroll
        for (int pl = 0; pl < 9; pl++) {
            int ky = pl / 3, kx = pl % 3;
            size_t fbase = ((size_t)(pl * CH_TOT + chunk) * G + g0) * 512 + lane * 8;
            short8 Ah0 = *(const short8*)(whi + fbase);
            short8 Ah1 = *(const short8*)(whi + fbase + 512);
            short8 Al0 = *(const short8*)(wlo + fbase);
            short8 Al1 = *(const short8*)(wlo + fbase + 512);
            int dp = ky * 17 + kx;
            #pragma unroll
            for (int nt = 0; nt < 4; nt++) {
                int p = pbase[nt] + dp;
                int u = p * 4 + (quad ^ ((p >> 1) & 3));
                short8 Bh = *(const short8*)&sA[u * 8];
                short8 Bl = *(const short8*)&sA[PLANE_E + u * 8];
                acc[0][nt] = MFMA16(Ah0, Bh, acc[0][nt]);
                acc[0][nt] = MFMA16(Ah0, Bl, acc[0][nt]);
                acc[0][nt] = MFMA16(Al0, Bh, acc[0][nt]);
                acc[1][nt] = MFMA16(Ah1, Bh, acc[1][nt]);
                acc[1][nt] = MFMA16(Ah1, Bl, acc[1][nt]);
                acc[1][nt] = MFMA16(Al1, Bh, acc[1][nt]);
            }
        }
    }
    int cob = cg * 128 + w * 32;
    #pragma unroll
    for (int ct = 0; ct < 2; ct++) {
        #pragma unroll
        for (int nt = 0; nt < 4; nt++) {
            if (oyl[nt] >= HOUT || oxl[nt] >= WOUT) continue;
            size_t base = ((size_t)(b * HOUT + oyl[nt]) * WOUT + oxl[nt]) * COUT
                          + cob + ct * 16 + quad * 4;
            if (PARTIAL) {
                *(f32x4*)&part[(size_t)ks * PSZ + base] = acc[ct][nt];
            } else {
                unsigned long long h64 = 0ull, l64 = 0ull;
                #pragma unroll
                for (int r = 0; r < 4; r++) {
                    float v = fmaxf(acc[ct][nt][r], 0.f);
                    unsigned short hh, ll; split_bf(v, hh, ll);
                    h64 |= ((unsigned long long)hh) << (16 * r);
                    l64 |= ((unsigned long long)ll) << (16 * r);
                }
                *(unsigned long long*)&ohi[base] = h64;
                *(unsigned long long*)&olo[base] = l64;
            }
        }
    }
}

// ---- reduce KS K-split fp32 partials -> ReLU -> hi/lo bf16 ----
template<int KS>
__global__ void reduceN_split(const float* __restrict__ p, unsigned short* __restrict__ oh,
                              unsigned short* __restrict__ ol, int n) {
    int n4 = n >> 2;
    int i = blockIdx.x * 256 + threadIdx.x;
    if (i >= n4) return;
    const float4* p4 = (const float4*)p;
    float4 s = p4[i];
    #pragma unroll
    for (int k = 1; k < KS; k++) {
        float4 t = p4[i + (size_t)k * n4];
        s.x += t.x; s.y += t.y; s.z += t.z; s.w += t.w;
    }
    float v[4] = { fmaxf(s.x,0.f), fmaxf(s.y,0.f), fmaxf(s.z,0.f), fmaxf(s.w,0.f) };
    unsigned long long h64 = 0ull, l64 = 0ull;
    #pragma unroll
    for (int r = 0; r < 4; r++) {
        unsigned short hh, ll; split_bf(v[r], hh, ll);
        h64 |= ((unsigned long long)hh) << (16 * r);
        l64 |= ((unsigned long long)ll) << (16 * r);
    }
    *(unsigned long long*)&oh[i * 4] = h64;
    *(unsigned long long*)&ol[i * 4] = l64;
}

// ---- 1x1 head ----
__global__ void head_kernel(const unsigned short* __restrict__ ah, const unsigned short* __restrict__ al,
                            const float* __restrict__ wh, float* __restrict__ pred) {
    int wave = threadIdx.x >> 6;
    int lane = threadIdx.x & 63;
    int cellid = blockIdx.x * 4 + wave;
    float acc[HEADC];
    #pragma unroll
    for (int c = 0; c < HEADC; c++) acc[c] = 0.f;
    for (int it = 0; it < 8; it++) {
        int ci = it * 64 + lane;
        size_t idx = (size_t)cellid * 512 + ci;
        float a = bf2f(ah[idx]) + bf2f(al[idx]);
        #pragma unroll
        for (int c = 0; c < HEADC; c++) acc[c] += a * wh[c * 512 + ci];
    }
    #pragma unroll
    for (int c = 0; c < HEADC; c++) {
        float v = acc[c];
        v += __shfl_down(v, 32); v += __shfl_down(v, 16); v += __shfl_down(v, 8);
        v += __shfl_down(v, 4);  v += __shfl_down(v, 2);  v += __shfl_down(v, 1);
        if (lane == 0) pred[(size_t)cellid * HEADC + c] = v;
    }
}

// ---- decode ----
__global__ void decode_kernel(const float* __restrict__ pred, float* __restrict__ out,
                              float* __restrict__ cls) {
    int i = blockIdx.x * 256 + threadIdx.x;
    if (i >= BATCH * NCELLS) return;
    const float* p = pred + (size_t)i * HEADC;
    int cell = i % NCELLS;
    int gx = cell % 14, gy = cell / 14;
    float conf = 1.f / (1.f + expf(-p[0]));
    float m = p[1];
    #pragma unroll
    for (int c = 1; c < NCLS; c++) m = fmaxf(m, p[1 + c]);
    float e[NCLS], s = 0.f;
    #pragma unroll
    for (int c = 0; c < NCLS; c++) { e[c] = expf(p[1 + c] - m); s += e[c]; }
    float inv = conf / s;
    #pragma unroll
    for (int c = 0; c < NCLS; c++) cls[(size_t)i * NCLS + c] = e[c] * inv;
    float cx = (1.f / (1.f + expf(-p[21])) + gx) * 32.f;
    float cy = (1.f / (1.f + expf(-p[22])) + gy) * 32.f;
    float w  = expf(p[23]) * 32.f;
    float h  = expf(p[24]) * 32.f;
    float x1 = (cx - 0.5f * w) / 448.f, y1 = (cy - 0.5f * h) / 448.f;
    float x2 = (cx + 0.5f * w) / 448.f, y2 = (cy + 0.5f * h) / 448.f;
    x1 = fminf(fmaxf(x1, 0.f), 1.f); y1 = fminf(fmaxf(y1, 0.f), 1.f);
    x2 = fminf(fmaxf(x2, 0.f), 1.f); y2 = fminf(fmaxf(y2, 0.f), 1.f);
    float* o = out + (size_t)i * 24;
    o[0] = x1; o[1] = y1; o[2] = x2; o[3] = y2;
}

// ---- IoU ----
__global__ void iou_kernel(const float* __restrict__ out, float* __restrict__ iou) {
    int idx = blockIdx.x * 256 + threadIdx.x;
    if (idx >= BATCH * NCELLS * NCELLS) return;
    int j = idx % NCELLS;
    int i = (idx / NCELLS) % NCELLS;
    int b = idx / (NCELLS * NCELLS);
    const float* bi = out + (((size_t)b * NCELLS) + i) * 24;
    const float* bj = out + (((size_t)b * NCELLS) + j) * 24;
    float ai = fmaxf(bi[2] - bi[0], 0.f) * fmaxf(bi[3] - bi[1], 0.f);
    float aj = fmaxf(bj[2] - bj[0], 0.f) * fmaxf(bj[3] - bj[1], 0.f);
    float ix1 = fmaxf(bi[0], bj[0]), iy1 = fmaxf(bi[1], bj[1]);
    float ix2 = fminf(bi[2], bj[2]), iy2 = fminf(bi[3], bj[3]);
    float inter = fmaxf(ix2 - ix1, 0.f) * fmaxf(iy2 - iy1, 0.f);
    iou[idx] = inter / (ai + aj - inter + 1e-14f);
}

// ---- NMS: bitmask formulation (R8) ----
// Phase 1: stable rank-sort (as before). Phase 2: build 196x4 u64 suppression
// bitmask in sorted space via ballots (parallel, latency-hidden, no syncs in
// the gather). Phase 3: greedy pass as pure register/LDS bit-ops, replicated
// in every thread (no barriers, no global reads) — kills the 196-iteration
// ~1000-cycle serial chain that made R7's nms 86us at 2% VALUBusy.
__global__ void nms_kernel(const float* __restrict__ cls, const float* __restrict__ iou,
                           float* __restrict__ out) {
    int b = blockIdx.x / NCLS;
    int c = blockIdx.x % NCLS;
    __shared__ float sc[NCELLS];
    __shared__ float ssort[NCELLS];
    __shared__ int   ord[NCELLS];
    __shared__ __align__(16) unsigned long long smask[NCELLS][4];
    int j = threadIdx.x;
    int lane = j & 63;
    int w = j >> 6;
    float sj = 0.f;
    if (j < NCELLS) {
        sj = cls[(((size_t)b * NCELLS) + j) * NCLS + c];
        sc[j] = sj;
    }
    __syncthreads();
    if (j < NCELLS) {
        int r = 0;
        for (int k = 0; k < NCELLS; k++) {
            float sk = sc[k];
            r += (sk > sj) || (sk == sj && k < j);   // stable descending rank
        }
        ord[r] = j; ssort[r] = sj;
    }
    __syncthreads();
    // phase 2: suppression bitmask rows (sorted space)
    const float* iob = iou + (size_t)b * NCELLS * NCELLS;
    int oc[4];
    #pragma unroll
    for (int k = 0; k < 4; k++) {
        int cidx = k * 64 + lane;
        oc[k] = (cidx < NCELLS) ? ord[cidx] : 0;
    }
    for (int i = w; i < NCELLS; i += 4) {
        const float* rowp = iob + ord[i] * NCELLS;
        #pragma unroll
        for (int k = 0; k < 4; k++) {
            int cidx = k * 64 + lane;
            bool sup = false;
            if (cidx < NCELLS && cidx > i)
                sup = rowp[oc[k]] > 0.5f;
            unsigned long long m = __ballot(sup);
            if (lane == 0) smask[i][k] = m;
        }
    }
    __syncthreads();
    // phase 3: replicated greedy bitmask loop
    unsigned long long keep[4];
    #pragma unroll
    for (int k = 0; k < 4; k++) {
        int cidx = k * 64 + lane;
        bool valid = (cidx < NCELLS) && (ssort[cidx] > 0.01f);
        keep[k] = __ballot(valid);
    }
    #pragma unroll
    for (int wi = 0; wi < 4; wi++) {
        int base = wi * 64;
        int lim = (NCELLS - base < 64) ? (NCELLS - base) : 64;
        for (int t = 0; t < lim; t++) {
            if ((keep[wi] >> t) & 1ull) {
                int i = base + t;
                keep[0] &= ~smask[i][0];
                keep[1] &= ~smask[i][1];
                keep[2] &= ~smask[i][2];
                keep[3] &= ~smask[i][3];
            }
        }
    }
    if (j < NCELLS) {
        bool kept = (keep[w] >> lane) & 1ull;      // j = w*64+lane
        out[(((size_t)b * NCELLS) + ord[j]) * 24 + 4 + c] = kept ? ssort[j] : 0.f;
    }
}

// ---- launch ----
extern "C" void kernel_launch(void* const* d_in, const int* in_sizes, int n_in,
                              void* d_out, int out_size, void* d_ws, size_t ws_size,
                              hipStream_t stream) {
    const float* x  = (const float*)d_in[0];
    const float* w1 = (const float*)d_in[1];
    const float* w2 = (const float*)d_in[2];
    const float* w3 = (const float*)d_in[3];
    const float* w4 = (const float*)d_in[4];
    const float* w5 = (const float*)d_in[5];
    const float* wh = (const float*)d_in[6];
    float* out = (float*)d_out;
    char* base = (char*)d_ws;

    // region A (0 .. 102,760,448)
    unsigned short* a1h = (unsigned short*)(base);
    unsigned short* a1l = a1h + 25690112;
    unsigned short* a3h = (unsigned short*)(base);          // overlays a1 (dead after conv2)
    unsigned short* a3l = a3h + 6422528;
    float* part4 = (float*)(base + 25690112);               // 2 x 3,211,264 fp32
    float* part5 = (float*)(base);                          // 8 x 802,816 fp32 (a3 dead)
    unsigned short* a5h = (unsigned short*)(base + 51380224);
    unsigned short* a5l = a5h + 802816;
    float* pred = (float*)(base + 54589440);
    float* clsb = (float*)(base + 54746240);
    float* ioub = (float*)(base + 54871680);
    // region B (102,760,448 .. 154,140,672)
    unsigned short* a2h = (unsigned short*)(base + 102760448);
    unsigned short* a2l = a2h + 12845056;
    unsigned short* a4h = (unsigned short*)(base + 102760448);  // overlays a2 (dead after conv3)
    unsigned short* a4l = a4h + 3211264;
    // weights
    unsigned short* w2h = (unsigned short*)(base + 154140672);
    unsigned short* w3h = w2h + 73728;
    unsigned short* w4h = w3h + 294912;
    unsigned short* w5h = w4h + 1179648;
    unsigned short* w2l = (unsigned short*)(base + 161955840);
    unsigned short* w3l = w2l + 73728;
    unsigned short* w4l = w3l + 294912;
    unsigned short* w5l = w4l + 1179648;

    prep_w<64, 128> <<<288,  256, 0, stream>>>(w2, w2h, w2l);
    prep_w<128, 256><<<1152, 256, 0, stream>>>(w3, w3h, w3l);
    prep_w<256, 512><<<4608, 256, 0, stream>>>(w4, w4h, w4l);
    prep_w<512, 512><<<9216, 256, 0, stream>>>(w5, w5h, w5l);

    conv1_kernel<<<12544, 256, 0, stream>>>(x, w1, a1h, a1l);

    conv_mfma<64, 128, 224, 224, 1, false><<<1568, 256, 0, stream>>>(
        a1h, a1l, w2h, w2l, a2h, a2l, nullptr);
    conv_mfma<128, 256, 112, 112, 1, false><<<784, 256, 0, stream>>>(
        a2h, a2l, w3h, w3l, a3h, a3l, nullptr);
    conv_mfma<256, 512, 56, 56, 2, true><<<1024, 256, 0, stream>>>(
        a3h, a3l, w4h, w4l, nullptr, nullptr, part4);
    reduceN_split<2><<<3136, 256, 0, stream>>>(part4, a4h, a4l, 3211264);
    conv_mfma<512, 512, 28, 28, 8, true><<<1024, 256, 0, stream>>>(
        a4h, a4l, w5h, w5l, nullptr, nullptr, part5);
    reduceN_split<8><<<784, 256, 0, stream>>>(part5, a5h, a5l, 802816);

    head_kernel<<<392, 256, 0, stream>>>(a5h, a5l, wh, pred);
    decode_kernel<<<7, 256, 0, stream>>>(pred, out, clsb);
    iou_kernel<<<1201, 256, 0, stream>>>(out, ioub);
    nms_kernel<<<160, 256, 0, stream>>>(clsb, ioub, out);
}